// Round 14
// baseline (386.095 us; speedup 1.0000x reference)
//
#include <hip/hip_runtime.h>

// ---------------------------------------------------------------------------
// UNet_old (graph U-Net, GMMConv K=10) on MI355X. fp32 in / fp32 out.
// R14: (1) all inter-layer activations out0..out3 stored fp16 — halves all
// gather traffic; out0 = 4.2MB now fits one XCD L2 (R13's aggf2-L5 FETCH
// showed ~37MB of out0-row misses). (2) L5 GEMM un-split (KS=1, 4096 waves)
// with fused bias+tanh — deletes part5 round-trip (75MB) + redact5 dispatch.
// aggf2 gathers half2/lane; LDS-staged fragment stores kept (WRITE stays
// exactly 126MB). L4 keeps split-K; redact4 writes fp16 out3.
// ---------------------------------------------------------------------------

#define N0C 65536
#define N1C 8192
#define N2C 1024
#define KK 10

typedef _Float16 half2t __attribute__((ext_vector_type(2)));
typedef _Float16 half4 __attribute__((ext_vector_type(4)));
typedef _Float16 f16x8 __attribute__((ext_vector_type(8)));
typedef float f32x4 __attribute__((ext_vector_type(4)));

static inline int cdiv(long long a, long long b) { return (int)((a + b - 1) / b); }

// fragment-tile index (in f16x8 units) for matrix row r, k-index kd.
__device__ __forceinline__ size_t fragi(int r, int kd, int KDT) {
    return ((size_t)(r >> 4) * KDT + (kd >> 5)) * 64 + ((kd >> 3) & 3) * 16 + (r & 15);
}

// ---------------- batched CSR build (3 graphs) ----------------

__global__ __launch_bounds__(256)
void k_hist3(const int* __restrict__ d1, const int* __restrict__ d2,
             const int* __restrict__ d3, int* __restrict__ g1,
             int* __restrict__ g2, int* __restrict__ g3,
             int E1, int E2, int E3) {
    int i = blockIdx.x * 256 + threadIdx.x;
    if (i < E1) atomicAdd(&g1[d1[i]], 1);
    else if (i < E1 + E2) atomicAdd(&g2[d2[i - E1]], 1);
    else if (i < E1 + E2 + E3) atomicAdd(&g3[d3[i - E1 - E2]], 1);
}

__device__ __forceinline__ void map_graph(int b, int& lb, int& gi) {
    if (b < 256) { gi = 0; lb = b; }
    else if (b < 288) { gi = 1; lb = b - 256; }
    else { gi = 2; lb = b - 288; }
}

__global__ __launch_bounds__(256)
void k_scan1_3(const int* __restrict__ deg1, int* __restrict__ off1,
               const int* __restrict__ deg2, int* __restrict__ off2,
               const int* __restrict__ deg3, int* __restrict__ off3,
               int* __restrict__ part) {
    __shared__ int s[256];
    int lb, gi; map_graph(blockIdx.x, lb, gi);
    const int* deg = gi == 0 ? deg1 : (gi == 1 ? deg2 : deg3);
    int* off = gi == 0 ? off1 : (gi == 1 ? off2 : off3);
    int* prt = part + (gi == 0 ? 0 : (gi == 1 ? 256 : 288));
    int i = lb * 256 + threadIdx.x;
    int v = deg[i];
    s[threadIdx.x] = v;
    __syncthreads();
#pragma unroll
    for (int d = 1; d < 256; d <<= 1) {
        int t = (threadIdx.x >= d) ? s[threadIdx.x - d] : 0;
        __syncthreads();
        s[threadIdx.x] += t;
        __syncthreads();
    }
    off[i] = s[threadIdx.x] - v;
    if (threadIdx.x == 255) prt[lb] = s[255];
}

__global__ __launch_bounds__(256)
void k_scan2_3(int* __restrict__ part) {
    __shared__ int s[256];
    int nb = blockIdx.x == 0 ? 256 : (blockIdx.x == 1 ? 32 : 4);
    int* p = part + (blockIdx.x == 0 ? 0 : (blockIdx.x == 1 ? 256 : 288));
    int v = (threadIdx.x < nb) ? p[threadIdx.x] : 0;
    s[threadIdx.x] = v;
    __syncthreads();
#pragma unroll
    for (int d = 1; d < 256; d <<= 1) {
        int t = (threadIdx.x >= d) ? s[threadIdx.x - d] : 0;
        __syncthreads();
        s[threadIdx.x] += t;
        __syncthreads();
    }
    if (threadIdx.x < nb) p[threadIdx.x] = s[threadIdx.x] - v;
}

__global__ __launch_bounds__(256)
void k_scan3_3(int* __restrict__ off1, int* __restrict__ off2, int* __restrict__ off3,
               const int* __restrict__ part,
               const int* __restrict__ deg1, const int* __restrict__ deg2,
               const int* __restrict__ deg3,
               float* __restrict__ inv1, float* __restrict__ inv2,
               float* __restrict__ inv3, int E1, int E2, int E3) {
    int lb, gi; map_graph(blockIdx.x, lb, gi);
    int* off = gi == 0 ? off1 : (gi == 1 ? off2 : off3);
    const int* deg = gi == 0 ? deg1 : (gi == 1 ? deg2 : deg3);
    float* inv = gi == 0 ? inv1 : (gi == 1 ? inv2 : inv3);
    const int* prt = part + (gi == 0 ? 0 : (gi == 1 ? 256 : 288));
    int n = gi == 0 ? N0C : (gi == 1 ? N1C : N2C);
    int E = gi == 0 ? E1 : (gi == 1 ? E2 : E3);
    int i = lb * 256 + threadIdx.x;
    off[i] += prt[lb];
    inv[i] = 1.0f / fmaxf((float)deg[i], 1.0f);
    if (i == n - 1) off[n] = E;
}

__global__ __launch_bounds__(256)
void k_scatter3(const int* __restrict__ s1, const int* __restrict__ d1,
                const float* __restrict__ p1, const int* __restrict__ o1,
                int* __restrict__ c1, int* __restrict__ cs1, float2* __restrict__ cp1,
                const int* __restrict__ s2, const int* __restrict__ d2,
                const float* __restrict__ p2, const int* __restrict__ o2,
                int* __restrict__ c2, int* __restrict__ cs2, float2* __restrict__ cp2,
                const int* __restrict__ s3, const int* __restrict__ d3,
                const float* __restrict__ p3, const int* __restrict__ o3,
                int* __restrict__ c3, int* __restrict__ cs3, float2* __restrict__ cp3,
                int E1, int E2, int E3) {
    int i = blockIdx.x * 256 + threadIdx.x;
    const int* src; const int* dst; const float* pk; const int* off;
    int* cur; int* csrc; float2* cpk; int e;
    if (i < E1) { src = s1; dst = d1; pk = p1; off = o1; cur = c1; csrc = cs1; cpk = cp1; e = i; }
    else if (i < E1 + E2) { src = s2; dst = d2; pk = p2; off = o2; cur = c2; csrc = cs2; cpk = cp2; e = i - E1; }
    else if (i < E1 + E2 + E3) { src = s3; dst = d3; pk = p3; off = o3; cur = c3; csrc = cs3; cpk = cp3; e = i - E1 - E2; }
    else return;
    int d = dst[e];
    int p = off[d] + atomicAdd(&cur[d], 1);
    csrc[p] = src[e];
    cpk[p] = reinterpret_cast<const float2*>(pk)[e];
}

// ---------------- batched gw precompute (5 layer-graph pairs) --------------
__global__ __launch_bounds__(256)
void k_gw(const float2* __restrict__ cp1, const float2* __restrict__ cp2,
          const float2* __restrict__ cp3,
          const float* __restrict__ mu1, const float* __restrict__ is1,
          const float* __restrict__ mu5, const float* __restrict__ is5,
          const float* __restrict__ mu2, const float* __restrict__ is2,
          const float* __restrict__ mu4, const float* __restrict__ is4,
          const float* __restrict__ mu3, const float* __restrict__ is3,
          float* __restrict__ g1, float* __restrict__ g5, float* __restrict__ g2,
          float* __restrict__ g4, float* __restrict__ g3,
          int E1, int E2, int E3) {
    int i = blockIdx.x * 256 + threadIdx.x;
    const float2* cp; const float* mu; const float* isg; float* g; int e;
    if (i < E1) { cp = cp1; mu = mu1; isg = is1; g = g1; e = i; }
    else if (i < 2 * E1) { cp = cp1; mu = mu5; isg = is5; g = g5; e = i - E1; }
    else if (i < 2 * E1 + E2) { cp = cp2; mu = mu2; isg = is2; g = g2; e = i - 2 * E1; }
    else if (i < 2 * E1 + 2 * E2) { cp = cp2; mu = mu4; isg = is4; g = g4; e = i - 2 * E1 - E2; }
    else if (i < 2 * E1 + 2 * E2 + E3) { cp = cp3; mu = mu3; isg = is3; g = g3; e = i - 2 * E1 - 2 * E2; }
    else return;
    float2 pk = cp[e];
    float o[KK];
#pragma unroll
    for (int k = 0; k < KK; ++k) {
        float dx = (pk.x - mu[2 * k]) * isg[2 * k];
        float dy = (pk.y - mu[2 * k + 1]) * isg[2 * k + 1];
        o[k] = __expf(-0.5f * (dx * dx + dy * dy));
    }
    float4* gp = reinterpret_cast<float4*>(g + (size_t)e * 12);
    gp[0] = make_float4(o[0], o[1], o[2], o[3]);
    gp[1] = make_float4(o[4], o[5], o[6], o[7]);
    gp[2] = make_float4(o[8], o[9], 0.f, 0.f);
}

#define LOAD_G(gw, j, G)                                                     \
    float G[KK];                                                             \
    {                                                                        \
        const float4* gp_ = reinterpret_cast<const float4*>((gw) + (size_t)(j) * 12); \
        float4 g0_ = gp_[0], g1_ = gp_[1]; float2 g2_ = *reinterpret_cast<const float2*>(gp_ + 2); \
        G[0] = g0_.x; G[1] = g0_.y; G[2] = g0_.z; G[3] = g0_.w;              \
        G[4] = g1_.x; G[5] = g1_.y; G[6] = g1_.z; G[7] = g1_.w;              \
        G[8] = g2_.x; G[9] = g2_.y;                                          \
    }

// ---------------- batched weight prep -> B-fragment tiles ----------------
__global__ __launch_bounds__(256)
void k_prep_wt(const float* __restrict__ W1, const float* __restrict__ W2,
               const float* __restrict__ W3, const float* __restrict__ W4,
               const float* __restrict__ W5,
               _Float16* __restrict__ T2,
               _Float16* __restrict__ T3, _Float16* __restrict__ T4,
               _Float16* __restrict__ T5) {
    int id = blockIdx.x * 256 + threadIdx.x;
    if (id < 20480) {                      // Wt2: F=64, KD=320 (Cin=32)
        int f = id / 320, kc = id % 320;
        T2[fragi(f, kc, 10) * 8 + (kc & 7)] = (_Float16)W2[(kc % 32) * 640 + (kc / 32) * 64 + f];
        return;
    }
    id -= 20480;
    if (id < 81920) {                      // Wt3: F=128, KD=640 (Cin=64)
        int f = id / 640, kc = id % 640;
        T3[fragi(f, kc, 20) * 8 + (kc & 7)] = (_Float16)W3[(kc % 64) * 1280 + (kc / 64) * 128 + f];
        return;
    }
    id -= 81920;
    if (id < 122880) {                     // Wt4: F=64, KD=1920 (Cin=192)
        int f = id / 1920, kc = id % 1920;
        T4[fragi(f, kc, 60) * 8 + (kc & 7)] = (_Float16)W4[(kc % 192) * 640 + (kc / 192) * 64 + f];
        return;
    }
    id -= 122880;
    if (id < 46080) {                      // Wt5: F=48 (store 40), KD=960 (Cin=96)
        int f = id / 960, kc = id % 960;
        float v = (f < 40) ? W5[(kc % 96) * 400 + (kc / 96) * 40 + f] : 0.0f;
        T5[fragi(f, kc, 30) * 8 + (kc & 7)] = (_Float16)v;
    }
}

// ---------------- L1 fused: aggregate (Cin=2) + mini-GEMM + bias + relu ----
__global__ __launch_bounds__(256, 4)
void k_l1(const float* __restrict__ x, const int* __restrict__ off,
          const int* __restrict__ csrc, const float* __restrict__ gw,
          const float* __restrict__ inv, const float* __restrict__ W1,
          const float* __restrict__ b1, _Float16* __restrict__ out0) {
    __shared__ float Ws[640];
    __shared__ float bs[32];
    for (int i = threadIdx.x; i < 640; i += 256) Ws[i] = W1[i];
    if (threadIdx.x < 32) bs[threadIdx.x] = b1[threadIdx.x];
    __syncthreads();
    int n = blockIdx.x * 256 + threadIdx.x;
    float a0[KK], a1[KK];
#pragma unroll
    for (int k = 0; k < KK; ++k) { a0[k] = 0.f; a1[k] = 0.f; }
    int j0 = off[n], j1 = off[n + 1];
    for (int j = j0; j < j1; ++j) {
        int s = csrc[j];
        LOAD_G(gw, j, G)
        float2 xv = reinterpret_cast<const float2*>(x)[s];
#pragma unroll
        for (int k = 0; k < KK; ++k) {
            a0[k] = fmaf(G[k], xv.x, a0[k]);
            a1[k] = fmaf(G[k], xv.y, a1[k]);
        }
    }
    float iv = inv[n];
#pragma unroll
    for (int k = 0; k < KK; ++k) { a0[k] *= iv; a1[k] *= iv; }
    _Float16* orow = out0 + (size_t)n * 32;
#pragma unroll
    for (int f4 = 0; f4 < 8; ++f4) {
        float v0 = bs[f4 * 4], v1 = bs[f4 * 4 + 1], v2 = bs[f4 * 4 + 2], v3 = bs[f4 * 4 + 3];
#pragma unroll
        for (int k = 0; k < KK; ++k) {
            const float* w0 = Ws + k * 32 + f4 * 4;
            const float* w1 = w0 + 320;
            v0 += a0[k] * w0[0] + a1[k] * w1[0];
            v1 += a0[k] * w0[1] + a1[k] * w1[1];
            v2 += a0[k] * w0[2] + a1[k] * w1[2];
            v3 += a0[k] * w0[3] + a1[k] * w1[3];
        }
        half4 o;
        o[0] = (_Float16)fmaxf(v0, 0.f); o[1] = (_Float16)fmaxf(v1, 0.f);
        o[2] = (_Float16)fmaxf(v2, 0.f); o[3] = (_Float16)fmaxf(v3, 0.f);
        *reinterpret_cast<half4*>(orow + f4 * 4) = o;
    }
}

// ---------------- split aggregate-X (fp16 node-major src) for L2/L3 -------
template <int TPN>
__global__ __launch_bounds__(256, 4)
void k_aggx(const _Float16* __restrict__ xp, const int* __restrict__ off,
            const int* __restrict__ csrc, const float* __restrict__ gw,
            const float* __restrict__ inv, _Float16* __restrict__ agg, int N) {
    constexpr int CIN = TPN * 4;
    constexpr int KDT = KK * CIN / 32;
    int tid = threadIdx.x;
    int nl = tid / TPN, tt = tid - nl * TPN;
    int node = blockIdx.x * (256 / TPN) + nl;
    if (node >= N) return;
    float a[KK][4];
#pragma unroll
    for (int k = 0; k < KK; ++k)
#pragma unroll
        for (int e = 0; e < 4; ++e) a[k][e] = 0.f;
    int j0 = off[node], j1 = off[node + 1];
    for (int j = j0; j < j1; ++j) {
        int s = csrc[j];
        LOAD_G(gw, j, G)
        half4 hv = *reinterpret_cast<const half4*>(xp + (size_t)s * CIN + 4 * tt);
        float x0 = hv[0], x1 = hv[1], x2 = hv[2], x3 = hv[3];
#pragma unroll
        for (int k = 0; k < KK; ++k) {
            a[k][0] = fmaf(G[k], x0, a[k][0]);
            a[k][1] = fmaf(G[k], x1, a[k][1]);
            a[k][2] = fmaf(G[k], x2, a[k][2]);
            a[k][3] = fmaf(G[k], x3, a[k][3]);
        }
    }
    float iv = inv[node];
#pragma unroll
    for (int k = 0; k < KK; ++k) {
        half4 o;
        o[0] = (_Float16)(a[k][0] * iv); o[1] = (_Float16)(a[k][1] * iv);
        o[2] = (_Float16)(a[k][2] * iv); o[3] = (_Float16)(a[k][3] * iv);
        int kd = k * CIN + 4 * tt;
        *reinterpret_cast<half4*>(agg + fragi(node, kd, KDT) * 8 + (kd & 7)) = o;
    }
}

// ---------------- L4/L5 aggregate v5: wave-per-node, fp16 X, LDS store ----
template <int CA, int CB>
__global__ __launch_bounds__(1024)
void k_aggf2(const _Float16* __restrict__ xA, const _Float16* __restrict__ xB,
             const int* __restrict__ off, const int* __restrict__ csrc,
             const float* __restrict__ gw, const float* __restrict__ inv,
             _Float16* __restrict__ agg, int nodeBase) {
    constexpr int CIN = CA + CB;
    constexpr int PAIRS = CIN / 2;
    constexpr int P = (PAIRS + 63) / 64;
    constexpr int KDT = KK * CIN / 32;
    constexpr int STRIDE = KK * CIN + 8;
    __shared__ _Float16 lds[16 * STRIDE];
    const int lane = threadIdx.x & 63;
    const int wv = threadIdx.x >> 6;
    const int node = __builtin_amdgcn_readfirstlane(nodeBase + blockIdx.x * 16 + wv);
    float a[KK][2 * P];
#pragma unroll
    for (int k = 0; k < KK; ++k)
#pragma unroll
        for (int p = 0; p < 2 * P; ++p) a[k][p] = 0.f;
    int j0 = __builtin_amdgcn_readfirstlane(off[node]);
    int j1 = __builtin_amdgcn_readfirstlane(off[node + 1]);
    for (int j = j0; j < j1; ++j) {
        int s = __builtin_amdgcn_readfirstlane(csrc[j]);
        LOAD_G(gw, j, G)
        float x0[P], x1[P];
#pragma unroll
        for (int p = 0; p < P; ++p) {
            int c0 = 2 * (lane + 64 * p);
            x0[p] = 0.f; x1[p] = 0.f;
            if (c0 < CIN) {
                const _Float16* qp = (c0 < CA) ? (xA + (size_t)(s >> 3) * CA + c0)
                                               : (xB + (size_t)s * CB + (c0 - CA));
                half2t hv = *reinterpret_cast<const half2t*>(qp);
                x0[p] = hv[0]; x1[p] = hv[1];
            }
        }
#pragma unroll
        for (int k = 0; k < KK; ++k)
#pragma unroll
            for (int p = 0; p < P; ++p) {
                a[k][2 * p] = fmaf(G[k], x0[p], a[k][2 * p]);
                a[k][2 * p + 1] = fmaf(G[k], x1[p], a[k][2 * p + 1]);
            }
    }
    float iv = inv[node];
#pragma unroll
    for (int k = 0; k < KK; ++k)
#pragma unroll
        for (int p = 0; p < P; ++p) {
            int c0 = 2 * (lane + 64 * p);
            if (c0 < CIN) {
                half2t o;
                o[0] = (_Float16)(a[k][2 * p] * iv);
                o[1] = (_Float16)(a[k][2 * p + 1] * iv);
                *reinterpret_cast<half2t*>(&lds[wv * STRIDE + k * CIN + c0]) = o;
            }
        }
    __syncthreads();
    f16x8* ag = reinterpret_cast<f16x8*>(agg);
    for (int s = threadIdx.x; s < KDT * 64; s += 1024) {
        int t = s >> 6, l = s & 63;
        int nd = l & 15, q = l >> 4;
        f16x8 v = *reinterpret_cast<const f16x8*>(&lds[nd * STRIDE + t * 32 + q * 8]);
        ag[((size_t)blockIdx.x * KDT + t) * 64 + l] = v;
    }
}

// ---------------- pipelined split-K MFMA GEMM (fragment-tile operands) -----
// OUTH: 0 = fp32 out, 1 = fp16 out (KS==1 path only).
template <int WB, int NT, int ITERS, int KS, int ACT, int FST, int OUTH>
__global__ __launch_bounds__(WB * 64)
void k_gemm2(const _Float16* __restrict__ A, const _Float16* __restrict__ B,
             const float* __restrict__ bias, void* __restrict__ outv, int M) {
    constexpr int KDT = KS * ITERS;
    constexpr int F = NT * 16;
    const int lane = threadIdx.x & 63;
    const int wv = threadIdx.x >> 6;
    const int lm = lane & 15;
    const int q = lane >> 4;
    const int ks = blockIdx.x;
    const int t0 = ks * ITERS;
    const size_t m0 = (size_t)blockIdx.y * (WB * 16) + wv * 16;
    const size_t mblk = m0 >> 4;
    f32x4 acc[NT];
#pragma unroll
    for (int t = 0; t < NT; ++t) acc[t] = (f32x4){0.f, 0.f, 0.f, 0.f};
    const f16x8* ap = (const f16x8*)A + (mblk * KDT + t0) * 64 + lane;
    const f16x8* bp = (const f16x8*)B + (size_t)t0 * 64 + lane;
    f16x8 af = ap[0];
    f16x8 bf[NT];
#pragma unroll
    for (int t = 0; t < NT; ++t) bf[t] = bp[(size_t)t * KDT * 64];
#pragma unroll
    for (int i = 0; i < ITERS; ++i) {
        f16x8 afn; f16x8 bfn[NT];
        if (i + 1 < ITERS) {
            afn = ap[(size_t)(i + 1) * 64];
#pragma unroll
            for (int t = 0; t < NT; ++t)
                bfn[t] = bp[((size_t)t * KDT + i + 1) * 64];
        }
#pragma unroll
        for (int t = 0; t < NT; ++t)
            acc[t] = __builtin_amdgcn_mfma_f32_16x16x32_f16(af, bf[t], acc[t], 0, 0, 0);
        af = afn;
#pragma unroll
        for (int t = 0; t < NT; ++t) bf[t] = bfn[t];
    }
    if (KS == 1) {
#pragma unroll
        for (int t = 0; t < NT; ++t) {
            int f = t * 16 + lm;
            if (f < FST) {
                float b = bias ? bias[f] : 0.0f;
#pragma unroll
                for (int r = 0; r < 4; ++r) {
                    float v = acc[t][r] + b;
                    v = (ACT == 1) ? tanhf(v) : fmaxf(v, 0.0f);
                    if (OUTH) ((_Float16*)outv)[(m0 + q * 4 + r) * (size_t)FST + f] = (_Float16)v;
                    else ((float*)outv)[(m0 + q * 4 + r) * (size_t)FST + f] = v;
                }
            }
        }
    } else {
        float* pout = (float*)outv + (size_t)ks * M * F;
#pragma unroll
        for (int t = 0; t < NT; ++t) {
            int f = t * 16 + lm;
#pragma unroll
            for (int r = 0; r < 4; ++r)
                pout[(m0 + q * 4 + r) * (size_t)F + f] = acc[t][r];
        }
    }
}

// reduce split-K partials: out[m][f<FST] = act(sum_s part[s][m][f] + bias)
template <int KS, int F, int FST, int ACT, int OUTH>
__global__ __launch_bounds__(256)
void k_redact(const float* __restrict__ part, const float* __restrict__ bias,
              void* __restrict__ outv, int M) {
    int i = blockIdx.x * 256 + threadIdx.x;
    if (i >= M * FST) return;
    int m = i / FST, f = i - m * FST;
    float v = 0.0f;
#pragma unroll
    for (int s = 0; s < KS; ++s) v += part[((size_t)s * M + m) * F + f];
    if (bias) v += bias[f];
    v = (ACT == 1) ? tanhf(v) : fmaxf(v, 0.0f);
    if (OUTH) ((_Float16*)outv)[(size_t)m * FST + f] = (_Float16)v;
    else ((float*)outv)[(size_t)m * FST + f] = v;
}

// out[j,f] = max over the 8 fine nodes of group j — fp16 in, fp16 out.
__global__ __launch_bounds__(256)
void k_pool8h(const _Float16* __restrict__ in, _Float16* __restrict__ out, int total, int F) {
    int i = blockIdx.x * 256 + threadIdx.x;
    if (i >= total) return;
    int j = i / F;
    int f = i - j * F;
    const _Float16* p = in + (size_t)(j << 3) * F + f;
    float m = (float)p[0];
#pragma unroll
    for (int r = 1; r < 8; ++r) m = fmaxf(m, (float)p[(size_t)r * F]);
    out[i] = (_Float16)m;
}

extern "C" void kernel_launch(void* const* d_in, const int* in_sizes, int n_in,
                              void* d_out, int out_size, void* d_ws, size_t ws_size,
                              hipStream_t stream) {
    const float* n_feat = (const float*)d_in[0];
    const int* src1 = (const int*)d_in[1];
    const int* dst1 = (const int*)d_in[2];
    const float* pkor1 = (const float*)d_in[3];
    const int* src2 = (const int*)d_in[4];
    const int* dst2 = (const int*)d_in[5];
    const float* pkor2 = (const float*)d_in[6];
    const int* src3 = (const int*)d_in[7];
    const int* dst3 = (const int*)d_in[8];
    const float* pkor3 = (const float*)d_in[9];
    const float* W1 = (const float*)d_in[16];
    const float* mu1 = (const float*)d_in[17];
    const float* is1 = (const float*)d_in[18];
    const float* b1 = (const float*)d_in[19];
    const float* W2 = (const float*)d_in[20];
    const float* mu2 = (const float*)d_in[21];
    const float* is2 = (const float*)d_in[22];
    const float* W3 = (const float*)d_in[23];
    const float* mu3 = (const float*)d_in[24];
    const float* is3 = (const float*)d_in[25];
    const float* W4 = (const float*)d_in[26];
    const float* mu4 = (const float*)d_in[27];
    const float* is4 = (const float*)d_in[28];
    const float* W5 = (const float*)d_in[29];
    const float* mu5 = (const float*)d_in[30];
    const float* is5 = (const float*)d_in[31];
    const float* b5 = (const float*)d_in[32];

    const int E1 = in_sizes[1], E2 = in_sizes[4], E3 = in_sizes[7];
    const int NT_ = N0C + N1C + N2C;

    char* w = (char*)d_ws;
    auto alloc = [&](size_t bytes) {
        void* p = (void*)w;
        w += (bytes + 255) & ~(size_t)255;
        return p;
    };
    int* degs = (int*)alloc((size_t)NT_ * 2 * 4);
    int* deg1 = degs, *deg2 = degs + N0C, *deg3 = degs + N0C + N1C;
    int* cur1 = degs + NT_, *cur2 = cur1 + N0C, *cur3 = cur2 + N1C;
    int* off1 = (int*)alloc(((size_t)N0C + 1) * 4);
    int* off2 = (int*)alloc(((size_t)N1C + 1) * 4);
    int* off3 = (int*)alloc(((size_t)N2C + 1) * 4);
    int* part = (int*)alloc(292 * 4);
    int* csrc1 = (int*)alloc((size_t)E1 * 4);
    float2* cpk1 = (float2*)alloc((size_t)E1 * 8);
    int* csrc2 = (int*)alloc((size_t)E2 * 4);
    float2* cpk2 = (float2*)alloc((size_t)E2 * 8);
    int* csrc3 = (int*)alloc((size_t)E3 * 4);
    float2* cpk3 = (float2*)alloc((size_t)E3 * 8);
    float* inv1 = (float*)alloc((size_t)N0C * 4);
    float* inv2 = (float*)alloc((size_t)N1C * 4);
    float* inv3 = (float*)alloc((size_t)N2C * 4);
    float* g1 = (float*)alloc(((size_t)2 * E1 + 2 * E2 + E3) * 12 * 4);
    float* g5 = g1 + (size_t)E1 * 12;
    float* g2 = g5 + (size_t)E1 * 12;
    float* g4 = g2 + (size_t)E2 * 12;
    float* g3 = g4 + (size_t)E2 * 12;
    _Float16* out0 = (_Float16*)alloc((size_t)N0C * 32 * 2);
    _Float16* out1 = (_Float16*)alloc((size_t)N1C * 64 * 2);
    _Float16* out2 = (_Float16*)alloc((size_t)N2C * 128 * 2);
    _Float16* out3 = (_Float16*)alloc((size_t)N1C * 64 * 2);
    _Float16* hp1 = (_Float16*)alloc((size_t)N1C * 32 * 2);
    _Float16* hp2 = (_Float16*)alloc((size_t)N2C * 64 * 2);
    _Float16* agg2 = (_Float16*)alloc((size_t)N1C * 320 * 2);
    _Float16* agg3 = (_Float16*)alloc((size_t)N2C * 640 * 2);
    _Float16* Wt2 = (_Float16*)alloc((size_t)64 * 320 * 2);
    _Float16* Wt3 = (_Float16*)alloc((size_t)128 * 640 * 2);
    _Float16* Wt4 = (_Float16*)alloc((size_t)64 * 1920 * 2);
    _Float16* Wt5 = (_Float16*)alloc((size_t)48 * 960 * 2);
    size_t used = (size_t)(w - (char*)d_ws);
    size_t rem = (ws_size > used) ? (ws_size - used) : 0;
    _Float16* agg4 = (_Float16*)w;
    float* part4 = (float*)(w + (((size_t)N1C * 1920 * 2 + 255) & ~(size_t)255));
    int npass = 1;
    while ((size_t)(N0C / npass) * 1920 > rem && npass < 16) npass <<= 1;
    const int chunk = N0C / npass;
    _Float16* agg5 = (_Float16*)w;

    const int ET = E1 + E2 + E3;
    const int GT = 2 * E1 + 2 * E2 + E3;

    // ---- CSR build (batched) + weight prep + gw precompute
    hipMemsetAsync(degs, 0, (size_t)NT_ * 2 * 4, stream);
    k_prep_wt<<<cdiv(271360, 256), 256, 0, stream>>>(W1, W2, W3, W4, W5,
                                                     Wt2, Wt3, Wt4, Wt5);
    k_hist3<<<cdiv(ET, 256), 256, 0, stream>>>(dst1, dst2, dst3, deg1, deg2, deg3, E1, E2, E3);
    k_scan1_3<<<292, 256, 0, stream>>>(deg1, off1, deg2, off2, deg3, off3, part);
    k_scan2_3<<<3, 256, 0, stream>>>(part);
    k_scan3_3<<<292, 256, 0, stream>>>(off1, off2, off3, part, deg1, deg2, deg3,
                                       inv1, inv2, inv3, E1, E2, E3);
    k_scatter3<<<cdiv(ET, 256), 256, 0, stream>>>(
        src1, dst1, pkor1, off1, cur1, csrc1, cpk1,
        src2, dst2, pkor2, off2, cur2, csrc2, cpk2,
        src3, dst3, pkor3, off3, cur3, csrc3, cpk3, E1, E2, E3);
    k_gw<<<cdiv(GT, 256), 256, 0, stream>>>(
        cpk1, cpk2, cpk3, mu1, is1, mu5, is5, mu2, is2, mu4, is4, mu3, is3,
        g1, g5, g2, g4, g3, E1, E2, E3);

    // ---- L1 fused: aggregate + mini-GEMM + b1 + relu -> out0 (N0,32) fp16
    k_l1<<<N0C / 256, 256, 0, stream>>>(n_feat, off1, csrc1, g1, inv1, W1, b1, out0);

    // ---- L2: pool -> aggX (Cin=32) -> agg2; GEMM+relu -> out1 (N1,64) fp16
    k_pool8h<<<cdiv(N1C * 32, 256), 256, 0, stream>>>(out0, hp1, N1C * 32, 32);
    k_aggx<8><<<cdiv(N1C, 32), 256, 0, stream>>>(hp1, off2, csrc2, g2, inv2, agg2, N1C);
    k_gemm2<2, 4, 10, 1, 0, 64, 1><<<dim3(1, N1C / 32), 128, 0, stream>>>(agg2, Wt2, nullptr, out1, N1C);

    // ---- L3: pool -> aggX (Cin=64) -> agg3; GEMM+relu -> out2 (N2,128) fp16
    k_pool8h<<<cdiv(N2C * 64, 256), 256, 0, stream>>>(out1, hp2, N2C * 64, 64);
    k_aggx<16><<<cdiv(N2C, 16), 256, 0, stream>>>(hp2, off3, csrc3, g3, inv3, agg3, N2C);
    k_gemm2<1, 8, 20, 1, 0, 128, 1><<<dim3(1, N2C / 16), 64, 0, stream>>>(agg3, Wt3, nullptr, out2, N2C);

    // ---- L4: aggF v5 -> agg4; split-K GEMM (KS=4) -> part4; reduce -> out3 fp16
    k_aggf2<128, 64><<<N1C / 16, 1024, 0, stream>>>(
        out2, out1, off2, csrc2, g4, inv2, agg4, 0);
    k_gemm2<2, 4, 15, 4, 0, 64, 0><<<dim3(4, N1C / 32), 128, 0, stream>>>(agg4, Wt4, nullptr, part4, N1C);
    k_redact<4, 64, 64, 0, 1><<<cdiv(N1C * 64, 256), 256, 0, stream>>>(part4, nullptr, out3, N1C);

    // ---- L5: aggF v5 -> agg5 (chunked); fused GEMM (KS=1, ITERS=30,
    //      b5 + tanh) -> d_out fp32
    for (int p = 0; p < npass; ++p) {
        int base = p * chunk;
        k_aggf2<64, 32><<<chunk / 16, 1024, 0, stream>>>(
            out3, out0, off1, csrc1, g5, inv1, agg5, base);
        k_gemm2<4, 3, 30, 1, 1, 40, 0><<<dim3(1, chunk / 64), 256, 0, stream>>>(
            agg5, Wt5, b5, ((float*)d_out) + (size_t)base * 40, chunk);
    }
}

// Round 15
// 355.792 us; speedup vs baseline: 1.0852x; 1.0852x over previous
//
#include <hip/hip_runtime.h>

// ---------------------------------------------------------------------------
// UNet_old (graph U-Net, GMMConv K=10) on MI355X. fp32 in / fp32 out.
// R15: 2-edge-unrolled gather loops (MLP fix). R14 post-mortem: fp16 gather
// halved loads-in-flight per edge (P=2 -> 1) and aggf2-L5 regressed 61.5->72us
// while FETCH dropped — latency-bound, MLP-controlled. All four edge-loop
// kernels (k_l1, k_aggx, k_aggf2 L4/L5) now process 2 edges per iteration:
// csrc/gw/X loads for both edges issue before the FMA blocks (2x outstanding
// loads). fp16 activations + fragment layouts + LDS-staged stores kept.
// ---------------------------------------------------------------------------

#define N0C 65536
#define N1C 8192
#define N2C 1024
#define KK 10

typedef _Float16 half2t __attribute__((ext_vector_type(2)));
typedef _Float16 half4 __attribute__((ext_vector_type(4)));
typedef _Float16 f16x8 __attribute__((ext_vector_type(8)));
typedef float f32x4 __attribute__((ext_vector_type(4)));

static inline int cdiv(long long a, long long b) { return (int)((a + b - 1) / b); }

// fragment-tile index (in f16x8 units) for matrix row r, k-index kd.
__device__ __forceinline__ size_t fragi(int r, int kd, int KDT) {
    return ((size_t)(r >> 4) * KDT + (kd >> 5)) * 64 + ((kd >> 3) & 3) * 16 + (r & 15);
}

// ---------------- batched CSR build (3 graphs) ----------------

__global__ __launch_bounds__(256)
void k_hist3(const int* __restrict__ d1, const int* __restrict__ d2,
             const int* __restrict__ d3, int* __restrict__ g1,
             int* __restrict__ g2, int* __restrict__ g3,
             int E1, int E2, int E3) {
    int i = blockIdx.x * 256 + threadIdx.x;
    if (i < E1) atomicAdd(&g1[d1[i]], 1);
    else if (i < E1 + E2) atomicAdd(&g2[d2[i - E1]], 1);
    else if (i < E1 + E2 + E3) atomicAdd(&g3[d3[i - E1 - E2]], 1);
}

__device__ __forceinline__ void map_graph(int b, int& lb, int& gi) {
    if (b < 256) { gi = 0; lb = b; }
    else if (b < 288) { gi = 1; lb = b - 256; }
    else { gi = 2; lb = b - 288; }
}

__global__ __launch_bounds__(256)
void k_scan1_3(const int* __restrict__ deg1, int* __restrict__ off1,
               const int* __restrict__ deg2, int* __restrict__ off2,
               const int* __restrict__ deg3, int* __restrict__ off3,
               int* __restrict__ part) {
    __shared__ int s[256];
    int lb, gi; map_graph(blockIdx.x, lb, gi);
    const int* deg = gi == 0 ? deg1 : (gi == 1 ? deg2 : deg3);
    int* off = gi == 0 ? off1 : (gi == 1 ? off2 : off3);
    int* prt = part + (gi == 0 ? 0 : (gi == 1 ? 256 : 288));
    int i = lb * 256 + threadIdx.x;
    int v = deg[i];
    s[threadIdx.x] = v;
    __syncthreads();
#pragma unroll
    for (int d = 1; d < 256; d <<= 1) {
        int t = (threadIdx.x >= d) ? s[threadIdx.x - d] : 0;
        __syncthreads();
        s[threadIdx.x] += t;
        __syncthreads();
    }
    off[i] = s[threadIdx.x] - v;
    if (threadIdx.x == 255) prt[lb] = s[255];
}

__global__ __launch_bounds__(256)
void k_scan2_3(int* __restrict__ part) {
    __shared__ int s[256];
    int nb = blockIdx.x == 0 ? 256 : (blockIdx.x == 1 ? 32 : 4);
    int* p = part + (blockIdx.x == 0 ? 0 : (blockIdx.x == 1 ? 256 : 288));
    int v = (threadIdx.x < nb) ? p[threadIdx.x] : 0;
    s[threadIdx.x] = v;
    __syncthreads();
#pragma unroll
    for (int d = 1; d < 256; d <<= 1) {
        int t = (threadIdx.x >= d) ? s[threadIdx.x - d] : 0;
        __syncthreads();
        s[threadIdx.x] += t;
        __syncthreads();
    }
    if (threadIdx.x < nb) p[threadIdx.x] = s[threadIdx.x] - v;
}

__global__ __launch_bounds__(256)
void k_scan3_3(int* __restrict__ off1, int* __restrict__ off2, int* __restrict__ off3,
               const int* __restrict__ part,
               const int* __restrict__ deg1, const int* __restrict__ deg2,
               const int* __restrict__ deg3,
               float* __restrict__ inv1, float* __restrict__ inv2,
               float* __restrict__ inv3, int E1, int E2, int E3) {
    int lb, gi; map_graph(blockIdx.x, lb, gi);
    int* off = gi == 0 ? off1 : (gi == 1 ? off2 : off3);
    const int* deg = gi == 0 ? deg1 : (gi == 1 ? deg2 : deg3);
    float* inv = gi == 0 ? inv1 : (gi == 1 ? inv2 : inv3);
    const int* prt = part + (gi == 0 ? 0 : (gi == 1 ? 256 : 288));
    int n = gi == 0 ? N0C : (gi == 1 ? N1C : N2C);
    int E = gi == 0 ? E1 : (gi == 1 ? E2 : E3);
    int i = lb * 256 + threadIdx.x;
    off[i] += prt[lb];
    inv[i] = 1.0f / fmaxf((float)deg[i], 1.0f);
    if (i == n - 1) off[n] = E;
}

__global__ __launch_bounds__(256)
void k_scatter3(const int* __restrict__ s1, const int* __restrict__ d1,
                const float* __restrict__ p1, const int* __restrict__ o1,
                int* __restrict__ c1, int* __restrict__ cs1, float2* __restrict__ cp1,
                const int* __restrict__ s2, const int* __restrict__ d2,
                const float* __restrict__ p2, const int* __restrict__ o2,
                int* __restrict__ c2, int* __restrict__ cs2, float2* __restrict__ cp2,
                const int* __restrict__ s3, const int* __restrict__ d3,
                const float* __restrict__ p3, const int* __restrict__ o3,
                int* __restrict__ c3, int* __restrict__ cs3, float2* __restrict__ cp3,
                int E1, int E2, int E3) {
    int i = blockIdx.x * 256 + threadIdx.x;
    const int* src; const int* dst; const float* pk; const int* off;
    int* cur; int* csrc; float2* cpk; int e;
    if (i < E1) { src = s1; dst = d1; pk = p1; off = o1; cur = c1; csrc = cs1; cpk = cp1; e = i; }
    else if (i < E1 + E2) { src = s2; dst = d2; pk = p2; off = o2; cur = c2; csrc = cs2; cpk = cp2; e = i - E1; }
    else if (i < E1 + E2 + E3) { src = s3; dst = d3; pk = p3; off = o3; cur = c3; csrc = cs3; cpk = cp3; e = i - E1 - E2; }
    else return;
    int d = dst[e];
    int p = off[d] + atomicAdd(&cur[d], 1);
    csrc[p] = src[e];
    cpk[p] = reinterpret_cast<const float2*>(pk)[e];
}

// ---------------- batched gw precompute (5 layer-graph pairs) --------------
__global__ __launch_bounds__(256)
void k_gw(const float2* __restrict__ cp1, const float2* __restrict__ cp2,
          const float2* __restrict__ cp3,
          const float* __restrict__ mu1, const float* __restrict__ is1,
          const float* __restrict__ mu5, const float* __restrict__ is5,
          const float* __restrict__ mu2, const float* __restrict__ is2,
          const float* __restrict__ mu4, const float* __restrict__ is4,
          const float* __restrict__ mu3, const float* __restrict__ is3,
          float* __restrict__ g1, float* __restrict__ g5, float* __restrict__ g2,
          float* __restrict__ g4, float* __restrict__ g3,
          int E1, int E2, int E3) {
    int i = blockIdx.x * 256 + threadIdx.x;
    const float2* cp; const float* mu; const float* isg; float* g; int e;
    if (i < E1) { cp = cp1; mu = mu1; isg = is1; g = g1; e = i; }
    else if (i < 2 * E1) { cp = cp1; mu = mu5; isg = is5; g = g5; e = i - E1; }
    else if (i < 2 * E1 + E2) { cp = cp2; mu = mu2; isg = is2; g = g2; e = i - 2 * E1; }
    else if (i < 2 * E1 + 2 * E2) { cp = cp2; mu = mu4; isg = is4; g = g4; e = i - 2 * E1 - E2; }
    else if (i < 2 * E1 + 2 * E2 + E3) { cp = cp3; mu = mu3; isg = is3; g = g3; e = i - 2 * E1 - 2 * E2; }
    else return;
    float2 pk = cp[e];
    float o[KK];
#pragma unroll
    for (int k = 0; k < KK; ++k) {
        float dx = (pk.x - mu[2 * k]) * isg[2 * k];
        float dy = (pk.y - mu[2 * k + 1]) * isg[2 * k + 1];
        o[k] = __expf(-0.5f * (dx * dx + dy * dy));
    }
    float4* gp = reinterpret_cast<float4*>(g + (size_t)e * 12);
    gp[0] = make_float4(o[0], o[1], o[2], o[3]);
    gp[1] = make_float4(o[4], o[5], o[6], o[7]);
    gp[2] = make_float4(o[8], o[9], 0.f, 0.f);
}

#define LOAD_G(gw, j, G)                                                     \
    float G[KK];                                                             \
    {                                                                        \
        const float4* gp_ = reinterpret_cast<const float4*>((gw) + (size_t)(j) * 12); \
        float4 g0_ = gp_[0], g1_ = gp_[1]; float2 g2_ = *reinterpret_cast<const float2*>(gp_ + 2); \
        G[0] = g0_.x; G[1] = g0_.y; G[2] = g0_.z; G[3] = g0_.w;              \
        G[4] = g1_.x; G[5] = g1_.y; G[6] = g1_.z; G[7] = g1_.w;              \
        G[8] = g2_.x; G[9] = g2_.y;                                          \
    }

// ---------------- batched weight prep -> B-fragment tiles ----------------
__global__ __launch_bounds__(256)
void k_prep_wt(const float* __restrict__ W1, const float* __restrict__ W2,
               const float* __restrict__ W3, const float* __restrict__ W4,
               const float* __restrict__ W5,
               _Float16* __restrict__ T2,
               _Float16* __restrict__ T3, _Float16* __restrict__ T4,
               _Float16* __restrict__ T5) {
    int id = blockIdx.x * 256 + threadIdx.x;
    if (id < 20480) {                      // Wt2: F=64, KD=320 (Cin=32)
        int f = id / 320, kc = id % 320;
        T2[fragi(f, kc, 10) * 8 + (kc & 7)] = (_Float16)W2[(kc % 32) * 640 + (kc / 32) * 64 + f];
        return;
    }
    id -= 20480;
    if (id < 81920) {                      // Wt3: F=128, KD=640 (Cin=64)
        int f = id / 640, kc = id % 640;
        T3[fragi(f, kc, 20) * 8 + (kc & 7)] = (_Float16)W3[(kc % 64) * 1280 + (kc / 64) * 128 + f];
        return;
    }
    id -= 81920;
    if (id < 122880) {                     // Wt4: F=64, KD=1920 (Cin=192)
        int f = id / 1920, kc = id % 1920;
        T4[fragi(f, kc, 60) * 8 + (kc & 7)] = (_Float16)W4[(kc % 192) * 640 + (kc / 192) * 64 + f];
        return;
    }
    id -= 122880;
    if (id < 46080) {                      // Wt5: F=48 (store 40), KD=960 (Cin=96)
        int f = id / 960, kc = id % 960;
        float v = (f < 40) ? W5[(kc % 96) * 400 + (kc / 96) * 40 + f] : 0.0f;
        T5[fragi(f, kc, 30) * 8 + (kc & 7)] = (_Float16)v;
    }
}

// ---------------- L1 fused: aggregate (Cin=2) + mini-GEMM + bias + relu ----
// 2-edge unrolled gather (MLP x2).
__global__ __launch_bounds__(256, 3)
void k_l1(const float* __restrict__ x, const int* __restrict__ off,
          const int* __restrict__ csrc, const float* __restrict__ gw,
          const float* __restrict__ inv, const float* __restrict__ W1,
          const float* __restrict__ b1, _Float16* __restrict__ out0) {
    __shared__ float Ws[640];
    __shared__ float bs[32];
    for (int i = threadIdx.x; i < 640; i += 256) Ws[i] = W1[i];
    if (threadIdx.x < 32) bs[threadIdx.x] = b1[threadIdx.x];
    __syncthreads();
    int n = blockIdx.x * 256 + threadIdx.x;
    float a0[KK], a1[KK];
#pragma unroll
    for (int k = 0; k < KK; ++k) { a0[k] = 0.f; a1[k] = 0.f; }
    int j0 = off[n], j1 = off[n + 1];
    int j = j0;
    for (; j + 1 < j1; j += 2) {
        int sa = csrc[j];
        int sb = csrc[j + 1];
        LOAD_G(gw, j, Ga)
        LOAD_G(gw, j + 1, Gb)
        float2 xa = reinterpret_cast<const float2*>(x)[sa];
        float2 xb = reinterpret_cast<const float2*>(x)[sb];
#pragma unroll
        for (int k = 0; k < KK; ++k) {
            a0[k] = fmaf(Ga[k], xa.x, a0[k]);
            a1[k] = fmaf(Ga[k], xa.y, a1[k]);
            a0[k] = fmaf(Gb[k], xb.x, a0[k]);
            a1[k] = fmaf(Gb[k], xb.y, a1[k]);
        }
    }
    if (j < j1) {
        int sa = csrc[j];
        LOAD_G(gw, j, Ga)
        float2 xa = reinterpret_cast<const float2*>(x)[sa];
#pragma unroll
        for (int k = 0; k < KK; ++k) {
            a0[k] = fmaf(Ga[k], xa.x, a0[k]);
            a1[k] = fmaf(Ga[k], xa.y, a1[k]);
        }
    }
    float iv = inv[n];
#pragma unroll
    for (int k = 0; k < KK; ++k) { a0[k] *= iv; a1[k] *= iv; }
    _Float16* orow = out0 + (size_t)n * 32;
#pragma unroll
    for (int f4 = 0; f4 < 8; ++f4) {
        float v0 = bs[f4 * 4], v1 = bs[f4 * 4 + 1], v2 = bs[f4 * 4 + 2], v3 = bs[f4 * 4 + 3];
#pragma unroll
        for (int k = 0; k < KK; ++k) {
            const float* w0 = Ws + k * 32 + f4 * 4;
            const float* w1 = w0 + 320;
            v0 += a0[k] * w0[0] + a1[k] * w1[0];
            v1 += a0[k] * w0[1] + a1[k] * w1[1];
            v2 += a0[k] * w0[2] + a1[k] * w1[2];
            v3 += a0[k] * w0[3] + a1[k] * w1[3];
        }
        half4 o;
        o[0] = (_Float16)fmaxf(v0, 0.f); o[1] = (_Float16)fmaxf(v1, 0.f);
        o[2] = (_Float16)fmaxf(v2, 0.f); o[3] = (_Float16)fmaxf(v3, 0.f);
        *reinterpret_cast<half4*>(orow + f4 * 4) = o;
    }
}

// ---------------- split aggregate-X (fp16 node-major src), 2-edge unroll ---
template <int TPN>
__global__ __launch_bounds__(256, 3)
void k_aggx(const _Float16* __restrict__ xp, const int* __restrict__ off,
            const int* __restrict__ csrc, const float* __restrict__ gw,
            const float* __restrict__ inv, _Float16* __restrict__ agg, int N) {
    constexpr int CIN = TPN * 4;
    constexpr int KDT = KK * CIN / 32;
    int tid = threadIdx.x;
    int nl = tid / TPN, tt = tid - nl * TPN;
    int node = blockIdx.x * (256 / TPN) + nl;
    if (node >= N) return;
    float a[KK][4];
#pragma unroll
    for (int k = 0; k < KK; ++k)
#pragma unroll
        for (int e = 0; e < 4; ++e) a[k][e] = 0.f;
    int j0 = off[node], j1 = off[node + 1];
    int j = j0;
    for (; j + 1 < j1; j += 2) {
        int sa = csrc[j];
        int sb = csrc[j + 1];
        LOAD_G(gw, j, Ga)
        LOAD_G(gw, j + 1, Gb)
        half4 ha = *reinterpret_cast<const half4*>(xp + (size_t)sa * CIN + 4 * tt);
        half4 hb = *reinterpret_cast<const half4*>(xp + (size_t)sb * CIN + 4 * tt);
        float a0 = ha[0], a1 = ha[1], a2 = ha[2], a3 = ha[3];
        float b0 = hb[0], b1 = hb[1], b2 = hb[2], b3 = hb[3];
#pragma unroll
        for (int k = 0; k < KK; ++k) {
            a[k][0] = fmaf(Ga[k], a0, a[k][0]);
            a[k][1] = fmaf(Ga[k], a1, a[k][1]);
            a[k][2] = fmaf(Ga[k], a2, a[k][2]);
            a[k][3] = fmaf(Ga[k], a3, a[k][3]);
            a[k][0] = fmaf(Gb[k], b0, a[k][0]);
            a[k][1] = fmaf(Gb[k], b1, a[k][1]);
            a[k][2] = fmaf(Gb[k], b2, a[k][2]);
            a[k][3] = fmaf(Gb[k], b3, a[k][3]);
        }
    }
    if (j < j1) {
        int sa = csrc[j];
        LOAD_G(gw, j, Ga)
        half4 ha = *reinterpret_cast<const half4*>(xp + (size_t)sa * CIN + 4 * tt);
        float a0 = ha[0], a1 = ha[1], a2 = ha[2], a3 = ha[3];
#pragma unroll
        for (int k = 0; k < KK; ++k) {
            a[k][0] = fmaf(Ga[k], a0, a[k][0]);
            a[k][1] = fmaf(Ga[k], a1, a[k][1]);
            a[k][2] = fmaf(Ga[k], a2, a[k][2]);
            a[k][3] = fmaf(Ga[k], a3, a[k][3]);
        }
    }
    float iv = inv[node];
#pragma unroll
    for (int k = 0; k < KK; ++k) {
        half4 o;
        o[0] = (_Float16)(a[k][0] * iv); o[1] = (_Float16)(a[k][1] * iv);
        o[2] = (_Float16)(a[k][2] * iv); o[3] = (_Float16)(a[k][3] * iv);
        int kd = k * CIN + 4 * tt;
        *reinterpret_cast<half4*>(agg + fragi(node, kd, KDT) * 8 + (kd & 7)) = o;
    }
}

// ---------------- L4/L5 aggregate v6: wave-per-node, 2-edge unroll --------
template <int CA, int CB>
__global__ __launch_bounds__(1024)
void k_aggf2(const _Float16* __restrict__ xA, const _Float16* __restrict__ xB,
             const int* __restrict__ off, const int* __restrict__ csrc,
             const float* __restrict__ gw, const float* __restrict__ inv,
             _Float16* __restrict__ agg, int nodeBase) {
    constexpr int CIN = CA + CB;
    constexpr int PAIRS = CIN / 2;
    constexpr int P = (PAIRS + 63) / 64;
    constexpr int KDT = KK * CIN / 32;
    constexpr int STRIDE = KK * CIN + 8;
    __shared__ _Float16 lds[16 * STRIDE];
    const int lane = threadIdx.x & 63;
    const int wv = threadIdx.x >> 6;
    const int node = __builtin_amdgcn_readfirstlane(nodeBase + blockIdx.x * 16 + wv);
    float a[KK][2 * P];
#pragma unroll
    for (int k = 0; k < KK; ++k)
#pragma unroll
        for (int p = 0; p < 2 * P; ++p) a[k][p] = 0.f;
    int j0 = __builtin_amdgcn_readfirstlane(off[node]);
    int j1 = __builtin_amdgcn_readfirstlane(off[node + 1]);
    int j = j0;
    for (; j + 1 < j1; j += 2) {
        int sa = __builtin_amdgcn_readfirstlane(csrc[j]);
        int sb = __builtin_amdgcn_readfirstlane(csrc[j + 1]);
        LOAD_G(gw, j, Ga)
        LOAD_G(gw, j + 1, Gb)
        float xa0[P], xa1[P], xb0[P], xb1[P];
#pragma unroll
        for (int p = 0; p < P; ++p) {
            int c0 = 2 * (lane + 64 * p);
            xa0[p] = 0.f; xa1[p] = 0.f; xb0[p] = 0.f; xb1[p] = 0.f;
            if (c0 < CIN) {
                const _Float16* qa = (c0 < CA) ? (xA + (size_t)(sa >> 3) * CA + c0)
                                               : (xB + (size_t)sa * CB + (c0 - CA));
                const _Float16* qb = (c0 < CA) ? (xA + (size_t)(sb >> 3) * CA + c0)
                                               : (xB + (size_t)sb * CB + (c0 - CA));
                half2t ha = *reinterpret_cast<const half2t*>(qa);
                half2t hb = *reinterpret_cast<const half2t*>(qb);
                xa0[p] = ha[0]; xa1[p] = ha[1];
                xb0[p] = hb[0]; xb1[p] = hb[1];
            }
        }
#pragma unroll
        for (int k = 0; k < KK; ++k)
#pragma unroll
            for (int p = 0; p < P; ++p) {
                a[k][2 * p] = fmaf(Ga[k], xa0[p], a[k][2 * p]);
                a[k][2 * p + 1] = fmaf(Ga[k], xa1[p], a[k][2 * p + 1]);
                a[k][2 * p] = fmaf(Gb[k], xb0[p], a[k][2 * p]);
                a[k][2 * p + 1] = fmaf(Gb[k], xb1[p], a[k][2 * p + 1]);
            }
    }
    if (j < j1) {
        int sa = __builtin_amdgcn_readfirstlane(csrc[j]);
        LOAD_G(gw, j, Ga)
        float xa0[P], xa1[P];
#pragma unroll
        for (int p = 0; p < P; ++p) {
            int c0 = 2 * (lane + 64 * p);
            xa0[p] = 0.f; xa1[p] = 0.f;
            if (c0 < CIN) {
                const _Float16* qa = (c0 < CA) ? (xA + (size_t)(sa >> 3) * CA + c0)
                                               : (xB + (size_t)sa * CB + (c0 - CA));
                half2t ha = *reinterpret_cast<const half2t*>(qa);
                xa0[p] = ha[0]; xa1[p] = ha[1];
            }
        }
#pragma unroll
        for (int k = 0; k < KK; ++k)
#pragma unroll
            for (int p = 0; p < P; ++p) {
                a[k][2 * p] = fmaf(Ga[k], xa0[p], a[k][2 * p]);
                a[k][2 * p + 1] = fmaf(Ga[k], xa1[p], a[k][2 * p + 1]);
            }
    }
    float iv = inv[node];
#pragma unroll
    for (int k = 0; k < KK; ++k)
#pragma unroll
        for (int p = 0; p < P; ++p) {
            int c0 = 2 * (lane + 64 * p);
            if (c0 < CIN) {
                half2t o;
                o[0] = (_Float16)(a[k][2 * p] * iv);
                o[1] = (_Float16)(a[k][2 * p + 1] * iv);
                *reinterpret_cast<half2t*>(&lds[wv * STRIDE + k * CIN + c0]) = o;
            }
        }
    __syncthreads();
    f16x8* ag = reinterpret_cast<f16x8*>(agg);
    for (int s = threadIdx.x; s < KDT * 64; s += 1024) {
        int t = s >> 6, l = s & 63;
        int nd = l & 15, q = l >> 4;
        f16x8 v = *reinterpret_cast<const f16x8*>(&lds[nd * STRIDE + t * 32 + q * 8]);
        ag[((size_t)blockIdx.x * KDT + t) * 64 + l] = v;
    }
}

// ---------------- pipelined split-K MFMA GEMM (fragment-tile operands) -----
// OUTH: 0 = fp32 out, 1 = fp16 out (KS==1 path only).
template <int WB, int NT, int ITERS, int KS, int ACT, int FST, int OUTH>
__global__ __launch_bounds__(WB * 64)
void k_gemm2(const _Float16* __restrict__ A, const _Float16* __restrict__ B,
             const float* __restrict__ bias, void* __restrict__ outv, int M) {
    constexpr int KDT = KS * ITERS;
    constexpr int F = NT * 16;
    const int lane = threadIdx.x & 63;
    const int wv = threadIdx.x >> 6;
    const int lm = lane & 15;
    const int q = lane >> 4;
    const int ks = blockIdx.x;
    const int t0 = ks * ITERS;
    const size_t m0 = (size_t)blockIdx.y * (WB * 16) + wv * 16;
    const size_t mblk = m0 >> 4;
    f32x4 acc[NT];
#pragma unroll
    for (int t = 0; t < NT; ++t) acc[t] = (f32x4){0.f, 0.f, 0.f, 0.f};
    const f16x8* ap = (const f16x8*)A + (mblk * KDT + t0) * 64 + lane;
    const f16x8* bp = (const f16x8*)B + (size_t)t0 * 64 + lane;
    f16x8 af = ap[0];
    f16x8 bf[NT];
#pragma unroll
    for (int t = 0; t < NT; ++t) bf[t] = bp[(size_t)t * KDT * 64];
#pragma unroll
    for (int i = 0; i < ITERS; ++i) {
        f16x8 afn; f16x8 bfn[NT];
        if (i + 1 < ITERS) {
            afn = ap[(size_t)(i + 1) * 64];
#pragma unroll
            for (int t = 0; t < NT; ++t)
                bfn[t] = bp[((size_t)t * KDT + i + 1) * 64];
        }
#pragma unroll
        for (int t = 0; t < NT; ++t)
            acc[t] = __builtin_amdgcn_mfma_f32_16x16x32_f16(af, bf[t], acc[t], 0, 0, 0);
        af = afn;
#pragma unroll
        for (int t = 0; t < NT; ++t) bf[t] = bfn[t];
    }
    if (KS == 1) {
#pragma unroll
        for (int t = 0; t < NT; ++t) {
            int f = t * 16 + lm;
            if (f < FST) {
                float b = bias ? bias[f] : 0.0f;
#pragma unroll
                for (int r = 0; r < 4; ++r) {
                    float v = acc[t][r] + b;
                    v = (ACT == 1) ? tanhf(v) : fmaxf(v, 0.0f);
                    if (OUTH) ((_Float16*)outv)[(m0 + q * 4 + r) * (size_t)FST + f] = (_Float16)v;
                    else ((float*)outv)[(m0 + q * 4 + r) * (size_t)FST + f] = v;
                }
            }
        }
    } else {
        float* pout = (float*)outv + (size_t)ks * M * F;
#pragma unroll
        for (int t = 0; t < NT; ++t) {
            int f = t * 16 + lm;
#pragma unroll
            for (int r = 0; r < 4; ++r)
                pout[(m0 + q * 4 + r) * (size_t)F + f] = acc[t][r];
        }
    }
}

// reduce split-K partials: out[m][f<FST] = act(sum_s part[s][m][f] + bias)
template <int KS, int F, int FST, int ACT, int OUTH>
__global__ __launch_bounds__(256)
void k_redact(const float* __restrict__ part, const float* __restrict__ bias,
              void* __restrict__ outv, int M) {
    int i = blockIdx.x * 256 + threadIdx.x;
    if (i >= M * FST) return;
    int m = i / FST, f = i - m * FST;
    float v = 0.0f;
#pragma unroll
    for (int s = 0; s < KS; ++s) v += part[((size_t)s * M + m) * F + f];
    if (bias) v += bias[f];
    v = (ACT == 1) ? tanhf(v) : fmaxf(v, 0.0f);
    if (OUTH) ((_Float16*)outv)[(size_t)m * FST + f] = (_Float16)v;
    else ((float*)outv)[(size_t)m * FST + f] = v;
}

// out[j,f] = max over the 8 fine nodes of group j — fp16 in, fp16 out.
__global__ __launch_bounds__(256)
void k_pool8h(const _Float16* __restrict__ in, _Float16* __restrict__ out, int total, int F) {
    int i = blockIdx.x * 256 + threadIdx.x;
    if (i >= total) return;
    int j = i / F;
    int f = i - j * F;
    const _Float16* p = in + (size_t)(j << 3) * F + f;
    float m = (float)p[0];
#pragma unroll
    for (int r = 1; r < 8; ++r) m = fmaxf(m, (float)p[(size_t)r * F]);
    out[i] = (_Float16)m;
}

extern "C" void kernel_launch(void* const* d_in, const int* in_sizes, int n_in,
                              void* d_out, int out_size, void* d_ws, size_t ws_size,
                              hipStream_t stream) {
    const float* n_feat = (const float*)d_in[0];
    const int* src1 = (const int*)d_in[1];
    const int* dst1 = (const int*)d_in[2];
    const float* pkor1 = (const float*)d_in[3];
    const int* src2 = (const int*)d_in[4];
    const int* dst2 = (const int*)d_in[5];
    const float* pkor2 = (const float*)d_in[6];
    const int* src3 = (const int*)d_in[7];
    const int* dst3 = (const int*)d_in[8];
    const float* pkor3 = (const float*)d_in[9];
    const float* W1 = (const float*)d_in[16];
    const float* mu1 = (const float*)d_in[17];
    const float* is1 = (const float*)d_in[18];
    const float* b1 = (const float*)d_in[19];
    const float* W2 = (const float*)d_in[20];
    const float* mu2 = (const float*)d_in[21];
    const float* is2 = (const float*)d_in[22];
    const float* W3 = (const float*)d_in[23];
    const float* mu3 = (const float*)d_in[24];
    const float* is3 = (const float*)d_in[25];
    const float* W4 = (const float*)d_in[26];
    const float* mu4 = (const float*)d_in[27];
    const float* is4 = (const float*)d_in[28];
    const float* W5 = (const float*)d_in[29];
    const float* mu5 = (const float*)d_in[30];
    const float* is5 = (const float*)d_in[31];
    const float* b5 = (const float*)d_in[32];

    const int E1 = in_sizes[1], E2 = in_sizes[4], E3 = in_sizes[7];
    const int NT_ = N0C + N1C + N2C;

    char* w = (char*)d_ws;
    auto alloc = [&](size_t bytes) {
        void* p = (void*)w;
        w += (bytes + 255) & ~(size_t)255;
        return p;
    };
    int* degs = (int*)alloc((size_t)NT_ * 2 * 4);
    int* deg1 = degs, *deg2 = degs + N0C, *deg3 = degs + N0C + N1C;
    int* cur1 = degs + NT_, *cur2 = cur1 + N0C, *cur3 = cur2 + N1C;
    int* off1 = (int*)alloc(((size_t)N0C + 1) * 4);
    int* off2 = (int*)alloc(((size_t)N1C + 1) * 4);
    int* off3 = (int*)alloc(((size_t)N2C + 1) * 4);
    int* part = (int*)alloc(292 * 4);
    int* csrc1 = (int*)alloc((size_t)E1 * 4);
    float2* cpk1 = (float2*)alloc((size_t)E1 * 8);
    int* csrc2 = (int*)alloc((size_t)E2 * 4);
    float2* cpk2 = (float2*)alloc((size_t)E2 * 8);
    int* csrc3 = (int*)alloc((size_t)E3 * 4);
    float2* cpk3 = (float2*)alloc((size_t)E3 * 8);
    float* inv1 = (float*)alloc((size_t)N0C * 4);
    float* inv2 = (float*)alloc((size_t)N1C * 4);
    float* inv3 = (float*)alloc((size_t)N2C * 4);
    float* g1 = (float*)alloc(((size_t)2 * E1 + 2 * E2 + E3) * 12 * 4);
    float* g5 = g1 + (size_t)E1 * 12;
    float* g2 = g5 + (size_t)E1 * 12;
    float* g4 = g2 + (size_t)E2 * 12;
    float* g3 = g4 + (size_t)E2 * 12;
    _Float16* out0 = (_Float16*)alloc((size_t)N0C * 32 * 2);
    _Float16* out1 = (_Float16*)alloc((size_t)N1C * 64 * 2);
    _Float16* out2 = (_Float16*)alloc((size_t)N2C * 128 * 2);
    _Float16* out3 = (_Float16*)alloc((size_t)N1C * 64 * 2);
    _Float16* hp1 = (_Float16*)alloc((size_t)N1C * 32 * 2);
    _Float16* hp2 = (_Float16*)alloc((size_t)N2C * 64 * 2);
    _Float16* agg2 = (_Float16*)alloc((size_t)N1C * 320 * 2);
    _Float16* agg3 = (_Float16*)alloc((size_t)N2C * 640 * 2);
    _Float16* Wt2 = (_Float16*)alloc((size_t)64 * 320 * 2);
    _Float16* Wt3 = (_Float16*)alloc((size_t)128 * 640 * 2);
    _Float16* Wt4 = (_Float16*)alloc((size_t)64 * 1920 * 2);
    _Float16* Wt5 = (_Float16*)alloc((size_t)48 * 960 * 2);
    size_t used = (size_t)(w - (char*)d_ws);
    size_t rem = (ws_size > used) ? (ws_size - used) : 0;
    _Float16* agg4 = (_Float16*)w;
    float* part4 = (float*)(w + (((size_t)N1C * 1920 * 2 + 255) & ~(size_t)255));
    int npass = 1;
    while ((size_t)(N0C / npass) * 1920 > rem && npass < 16) npass <<= 1;
    const int chunk = N0C / npass;
    _Float16* agg5 = (_Float16*)w;

    const int ET = E1 + E2 + E3;
    const int GT = 2 * E1 + 2 * E2 + E3;

    // ---- CSR build (batched) + weight prep + gw precompute
    hipMemsetAsync(degs, 0, (size_t)NT_ * 2 * 4, stream);
    k_prep_wt<<<cdiv(271360, 256), 256, 0, stream>>>(W1, W2, W3, W4, W5,
                                                     Wt2, Wt3, Wt4, Wt5);
    k_hist3<<<cdiv(ET, 256), 256, 0, stream>>>(dst1, dst2, dst3, deg1, deg2, deg3, E1, E2, E3);
    k_scan1_3<<<292, 256, 0, stream>>>(deg1, off1, deg2, off2, deg3, off3, part);
    k_scan2_3<<<3, 256, 0, stream>>>(part);
    k_scan3_3<<<292, 256, 0, stream>>>(off1, off2, off3, part, deg1, deg2, deg3,
                                       inv1, inv2, inv3, E1, E2, E3);
    k_scatter3<<<cdiv(ET, 256), 256, 0, stream>>>(
        src1, dst1, pkor1, off1, cur1, csrc1, cpk1,
        src2, dst2, pkor2, off2, cur2, csrc2, cpk2,
        src3, dst3, pkor3, off3, cur3, csrc3, cpk3, E1, E2, E3);
    k_gw<<<cdiv(GT, 256), 256, 0, stream>>>(
        cpk1, cpk2, cpk3, mu1, is1, mu5, is5, mu2, is2, mu4, is4, mu3, is3,
        g1, g5, g2, g4, g3, E1, E2, E3);

    // ---- L1 fused: aggregate + mini-GEMM + b1 + relu -> out0 (N0,32) fp16
    k_l1<<<N0C / 256, 256, 0, stream>>>(n_feat, off1, csrc1, g1, inv1, W1, b1, out0);

    // ---- L2: pool -> aggX (Cin=32) -> agg2; GEMM+relu -> out1 (N1,64) fp16
    k_pool8h<<<cdiv(N1C * 32, 256), 256, 0, stream>>>(out0, hp1, N1C * 32, 32);
    k_aggx<8><<<cdiv(N1C, 32), 256, 0, stream>>>(hp1, off2, csrc2, g2, inv2, agg2, N1C);
    k_gemm2<2, 4, 10, 1, 0, 64, 1><<<dim3(1, N1C / 32), 128, 0, stream>>>(agg2, Wt2, nullptr, out1, N1C);

    // ---- L3: pool -> aggX (Cin=64) -> agg3; GEMM+relu -> out2 (N2,128) fp16
    k_pool8h<<<cdiv(N2C * 64, 256), 256, 0, stream>>>(out1, hp2, N2C * 64, 64);
    k_aggx<16><<<cdiv(N2C, 16), 256, 0, stream>>>(hp2, off3, csrc3, g3, inv3, agg3, N2C);
    k_gemm2<1, 8, 20, 1, 0, 128, 1><<<dim3(1, N2C / 16), 64, 0, stream>>>(agg3, Wt3, nullptr, out2, N2C);

    // ---- L4: aggF v6 -> agg4; split-K GEMM (KS=4) -> part4; reduce -> out3 fp16
    k_aggf2<128, 64><<<N1C / 16, 1024, 0, stream>>>(
        out2, out1, off2, csrc2, g4, inv2, agg4, 0);
    k_gemm2<2, 4, 15, 4, 0, 64, 0><<<dim3(4, N1C / 32), 128, 0, stream>>>(agg4, Wt4, nullptr, part4, N1C);
    k_redact<4, 64, 64, 0, 1><<<cdiv(N1C * 64, 256), 256, 0, stream>>>(part4, nullptr, out3, N1C);

    // ---- L5: aggF v6 -> agg5 (chunked); fused GEMM (KS=1, ITERS=30,
    //      b5 + tanh) -> d_out fp32
    for (int p = 0; p < npass; ++p) {
        int base = p * chunk;
        k_aggf2<64, 32><<<chunk / 16, 1024, 0, stream>>>(
            out3, out0, off1, csrc1, g5, inv1, agg5, base);
        k_gemm2<4, 3, 30, 1, 1, 40, 0><<<dim3(1, chunk / 64), 256, 0, stream>>>(
            agg5, Wt5, b5, ((float*)d_out) + (size_t)base * 40, chunk);
    }
}

// Round 16
// 343.911 us; speedup vs baseline: 1.1227x; 1.0345x over previous
//
#include <hip/hip_runtime.h>

// ---------------------------------------------------------------------------
// UNet_old (graph U-Net, GMMConv K=10) on MI355X. fp32 in / fp32 out.
// R16: k_aggf3 — csrc lane-preload + readlane (removes the csrc->X serial
// link: one coalesced load fetches the node's whole edge window; indices
// resolve from registers). L5 blocks reshaped to 8 waves x 2 nodes/wave
// (straggler efficiency 0.55 -> ~0.71, same 16-node LDS tile). L4 keeps
// 16x1 (62KB LDS). Everything else identical to R15 (fp16 activations,
// fragment-tile GEMM operands, LDS-staged stores, gw precompute).
// ---------------------------------------------------------------------------

#define N0C 65536
#define N1C 8192
#define N2C 1024
#define KK 10

typedef _Float16 half2t __attribute__((ext_vector_type(2)));
typedef _Float16 half4 __attribute__((ext_vector_type(4)));
typedef _Float16 f16x8 __attribute__((ext_vector_type(8)));
typedef float f32x4 __attribute__((ext_vector_type(4)));

static inline int cdiv(long long a, long long b) { return (int)((a + b - 1) / b); }

// fragment-tile index (in f16x8 units) for matrix row r, k-index kd.
__device__ __forceinline__ size_t fragi(int r, int kd, int KDT) {
    return ((size_t)(r >> 4) * KDT + (kd >> 5)) * 64 + ((kd >> 3) & 3) * 16 + (r & 15);
}

// ---------------- batched CSR build (3 graphs) ----------------

__global__ __launch_bounds__(256)
void k_hist3(const int* __restrict__ d1, const int* __restrict__ d2,
             const int* __restrict__ d3, int* __restrict__ g1,
             int* __restrict__ g2, int* __restrict__ g3,
             int E1, int E2, int E3) {
    int i = blockIdx.x * 256 + threadIdx.x;
    if (i < E1) atomicAdd(&g1[d1[i]], 1);
    else if (i < E1 + E2) atomicAdd(&g2[d2[i - E1]], 1);
    else if (i < E1 + E2 + E3) atomicAdd(&g3[d3[i - E1 - E2]], 1);
}

__device__ __forceinline__ void map_graph(int b, int& lb, int& gi) {
    if (b < 256) { gi = 0; lb = b; }
    else if (b < 288) { gi = 1; lb = b - 256; }
    else { gi = 2; lb = b - 288; }
}

__global__ __launch_bounds__(256)
void k_scan1_3(const int* __restrict__ deg1, int* __restrict__ off1,
               const int* __restrict__ deg2, int* __restrict__ off2,
               const int* __restrict__ deg3, int* __restrict__ off3,
               int* __restrict__ part) {
    __shared__ int s[256];
    int lb, gi; map_graph(blockIdx.x, lb, gi);
    const int* deg = gi == 0 ? deg1 : (gi == 1 ? deg2 : deg3);
    int* off = gi == 0 ? off1 : (gi == 1 ? off2 : off3);
    int* prt = part + (gi == 0 ? 0 : (gi == 1 ? 256 : 288));
    int i = lb * 256 + threadIdx.x;
    int v = deg[i];
    s[threadIdx.x] = v;
    __syncthreads();
#pragma unroll
    for (int d = 1; d < 256; d <<= 1) {
        int t = (threadIdx.x >= d) ? s[threadIdx.x - d] : 0;
        __syncthreads();
        s[threadIdx.x] += t;
        __syncthreads();
    }
    off[i] = s[threadIdx.x] - v;
    if (threadIdx.x == 255) prt[lb] = s[255];
}

__global__ __launch_bounds__(256)
void k_scan2_3(int* __restrict__ part) {
    __shared__ int s[256];
    int nb = blockIdx.x == 0 ? 256 : (blockIdx.x == 1 ? 32 : 4);
    int* p = part + (blockIdx.x == 0 ? 0 : (blockIdx.x == 1 ? 256 : 288));
    int v = (threadIdx.x < nb) ? p[threadIdx.x] : 0;
    s[threadIdx.x] = v;
    __syncthreads();
#pragma unroll
    for (int d = 1; d < 256; d <<= 1) {
        int t = (threadIdx.x >= d) ? s[threadIdx.x - d] : 0;
        __syncthreads();
        s[threadIdx.x] += t;
        __syncthreads();
    }
    if (threadIdx.x < nb) p[threadIdx.x] = s[threadIdx.x] - v;
}

__global__ __launch_bounds__(256)
void k_scan3_3(int* __restrict__ off1, int* __restrict__ off2, int* __restrict__ off3,
               const int* __restrict__ part,
               const int* __restrict__ deg1, const int* __restrict__ deg2,
               const int* __restrict__ deg3,
               float* __restrict__ inv1, float* __restrict__ inv2,
               float* __restrict__ inv3, int E1, int E2, int E3) {
    int lb, gi; map_graph(blockIdx.x, lb, gi);
    int* off = gi == 0 ? off1 : (gi == 1 ? off2 : off3);
    const int* deg = gi == 0 ? deg1 : (gi == 1 ? deg2 : deg3);
    float* inv = gi == 0 ? inv1 : (gi == 1 ? inv2 : inv3);
    const int* prt = part + (gi == 0 ? 0 : (gi == 1 ? 256 : 288));
    int n = gi == 0 ? N0C : (gi == 1 ? N1C : N2C);
    int E = gi == 0 ? E1 : (gi == 1 ? E2 : E3);
    int i = lb * 256 + threadIdx.x;
    off[i] += prt[lb];
    inv[i] = 1.0f / fmaxf((float)deg[i], 1.0f);
    if (i == n - 1) off[n] = E;
}

__global__ __launch_bounds__(256)
void k_scatter3(const int* __restrict__ s1, const int* __restrict__ d1,
                const float* __restrict__ p1, const int* __restrict__ o1,
                int* __restrict__ c1, int* __restrict__ cs1, float2* __restrict__ cp1,
                const int* __restrict__ s2, const int* __restrict__ d2,
                const float* __restrict__ p2, const int* __restrict__ o2,
                int* __restrict__ c2, int* __restrict__ cs2, float2* __restrict__ cp2,
                const int* __restrict__ s3, const int* __restrict__ d3,
                const float* __restrict__ p3, const int* __restrict__ o3,
                int* __restrict__ c3, int* __restrict__ cs3, float2* __restrict__ cp3,
                int E1, int E2, int E3) {
    int i = blockIdx.x * 256 + threadIdx.x;
    const int* src; const int* dst; const float* pk; const int* off;
    int* cur; int* csrc; float2* cpk; int e;
    if (i < E1) { src = s1; dst = d1; pk = p1; off = o1; cur = c1; csrc = cs1; cpk = cp1; e = i; }
    else if (i < E1 + E2) { src = s2; dst = d2; pk = p2; off = o2; cur = c2; csrc = cs2; cpk = cp2; e = i - E1; }
    else if (i < E1 + E2 + E3) { src = s3; dst = d3; pk = p3; off = o3; cur = c3; csrc = cs3; cpk = cp3; e = i - E1 - E2; }
    else return;
    int d = dst[e];
    int p = off[d] + atomicAdd(&cur[d], 1);
    csrc[p] = src[e];
    cpk[p] = reinterpret_cast<const float2*>(pk)[e];
}

// ---------------- batched gw precompute (5 layer-graph pairs) --------------
__global__ __launch_bounds__(256)
void k_gw(const float2* __restrict__ cp1, const float2* __restrict__ cp2,
          const float2* __restrict__ cp3,
          const float* __restrict__ mu1, const float* __restrict__ is1,
          const float* __restrict__ mu5, const float* __restrict__ is5,
          const float* __restrict__ mu2, const float* __restrict__ is2,
          const float* __restrict__ mu4, const float* __restrict__ is4,
          const float* __restrict__ mu3, const float* __restrict__ is3,
          float* __restrict__ g1, float* __restrict__ g5, float* __restrict__ g2,
          float* __restrict__ g4, float* __restrict__ g3,
          int E1, int E2, int E3) {
    int i = blockIdx.x * 256 + threadIdx.x;
    const float2* cp; const float* mu; const float* isg; float* g; int e;
    if (i < E1) { cp = cp1; mu = mu1; isg = is1; g = g1; e = i; }
    else if (i < 2 * E1) { cp = cp1; mu = mu5; isg = is5; g = g5; e = i - E1; }
    else if (i < 2 * E1 + E2) { cp = cp2; mu = mu2; isg = is2; g = g2; e = i - 2 * E1; }
    else if (i < 2 * E1 + 2 * E2) { cp = cp2; mu = mu4; isg = is4; g = g4; e = i - 2 * E1 - E2; }
    else if (i < 2 * E1 + 2 * E2 + E3) { cp = cp3; mu = mu3; isg = is3; g = g3; e = i - 2 * E1 - 2 * E2; }
    else return;
    float2 pk = cp[e];
    float o[KK];
#pragma unroll
    for (int k = 0; k < KK; ++k) {
        float dx = (pk.x - mu[2 * k]) * isg[2 * k];
        float dy = (pk.y - mu[2 * k + 1]) * isg[2 * k + 1];
        o[k] = __expf(-0.5f * (dx * dx + dy * dy));
    }
    float4* gp = reinterpret_cast<float4*>(g + (size_t)e * 12);
    gp[0] = make_float4(o[0], o[1], o[2], o[3]);
    gp[1] = make_float4(o[4], o[5], o[6], o[7]);
    gp[2] = make_float4(o[8], o[9], 0.f, 0.f);
}

#define LOAD_G(gw, j, G)                                                     \
    float G[KK];                                                             \
    {                                                                        \
        const float4* gp_ = reinterpret_cast<const float4*>((gw) + (size_t)(j) * 12); \
        float4 g0_ = gp_[0], g1_ = gp_[1]; float2 g2_ = *reinterpret_cast<const float2*>(gp_ + 2); \
        G[0] = g0_.x; G[1] = g0_.y; G[2] = g0_.z; G[3] = g0_.w;              \
        G[4] = g1_.x; G[5] = g1_.y; G[6] = g1_.z; G[7] = g1_.w;              \
        G[8] = g2_.x; G[9] = g2_.y;                                          \
    }

// ---------------- batched weight prep -> B-fragment tiles ----------------
__global__ __launch_bounds__(256)
void k_prep_wt(const float* __restrict__ W1, const float* __restrict__ W2,
               const float* __restrict__ W3, const float* __restrict__ W4,
               const float* __restrict__ W5,
               _Float16* __restrict__ T2,
               _Float16* __restrict__ T3, _Float16* __restrict__ T4,
               _Float16* __restrict__ T5) {
    int id = blockIdx.x * 256 + threadIdx.x;
    if (id < 20480) {                      // Wt2: F=64, KD=320 (Cin=32)
        int f = id / 320, kc = id % 320;
        T2[fragi(f, kc, 10) * 8 + (kc & 7)] = (_Float16)W2[(kc % 32) * 640 + (kc / 32) * 64 + f];
        return;
    }
    id -= 20480;
    if (id < 81920) {                      // Wt3: F=128, KD=640 (Cin=64)
        int f = id / 640, kc = id % 640;
        T3[fragi(f, kc, 20) * 8 + (kc & 7)] = (_Float16)W3[(kc % 64) * 1280 + (kc / 64) * 128 + f];
        return;
    }
    id -= 81920;
    if (id < 122880) {                     // Wt4: F=64, KD=1920 (Cin=192)
        int f = id / 1920, kc = id % 1920;
        T4[fragi(f, kc, 60) * 8 + (kc & 7)] = (_Float16)W4[(kc % 192) * 640 + (kc / 192) * 64 + f];
        return;
    }
    id -= 122880;
    if (id < 46080) {                      // Wt5: F=48 (store 40), KD=960 (Cin=96)
        int f = id / 960, kc = id % 960;
        float v = (f < 40) ? W5[(kc % 96) * 400 + (kc / 96) * 40 + f] : 0.0f;
        T5[fragi(f, kc, 30) * 8 + (kc & 7)] = (_Float16)v;
    }
}

// ---------------- L1 fused: aggregate (Cin=2) + mini-GEMM + bias + relu ----
__global__ __launch_bounds__(256, 3)
void k_l1(const float* __restrict__ x, const int* __restrict__ off,
          const int* __restrict__ csrc, const float* __restrict__ gw,
          const float* __restrict__ inv, const float* __restrict__ W1,
          const float* __restrict__ b1, _Float16* __restrict__ out0) {
    __shared__ float Ws[640];
    __shared__ float bs[32];
    for (int i = threadIdx.x; i < 640; i += 256) Ws[i] = W1[i];
    if (threadIdx.x < 32) bs[threadIdx.x] = b1[threadIdx.x];
    __syncthreads();
    int n = blockIdx.x * 256 + threadIdx.x;
    float a0[KK], a1[KK];
#pragma unroll
    for (int k = 0; k < KK; ++k) { a0[k] = 0.f; a1[k] = 0.f; }
    int j0 = off[n], j1 = off[n + 1];
    int j = j0;
    for (; j + 1 < j1; j += 2) {
        int sa = csrc[j];
        int sb = csrc[j + 1];
        LOAD_G(gw, j, Ga)
        LOAD_G(gw, j + 1, Gb)
        float2 xa = reinterpret_cast<const float2*>(x)[sa];
        float2 xb = reinterpret_cast<const float2*>(x)[sb];
#pragma unroll
        for (int k = 0; k < KK; ++k) {
            a0[k] = fmaf(Ga[k], xa.x, a0[k]);
            a1[k] = fmaf(Ga[k], xa.y, a1[k]);
            a0[k] = fmaf(Gb[k], xb.x, a0[k]);
            a1[k] = fmaf(Gb[k], xb.y, a1[k]);
        }
    }
    if (j < j1) {
        int sa = csrc[j];
        LOAD_G(gw, j, Ga)
        float2 xa = reinterpret_cast<const float2*>(x)[sa];
#pragma unroll
        for (int k = 0; k < KK; ++k) {
            a0[k] = fmaf(Ga[k], xa.x, a0[k]);
            a1[k] = fmaf(Ga[k], xa.y, a1[k]);
        }
    }
    float iv = inv[n];
#pragma unroll
    for (int k = 0; k < KK; ++k) { a0[k] *= iv; a1[k] *= iv; }
    _Float16* orow = out0 + (size_t)n * 32;
#pragma unroll
    for (int f4 = 0; f4 < 8; ++f4) {
        float v0 = bs[f4 * 4], v1 = bs[f4 * 4 + 1], v2 = bs[f4 * 4 + 2], v3 = bs[f4 * 4 + 3];
#pragma unroll
        for (int k = 0; k < KK; ++k) {
            const float* w0 = Ws + k * 32 + f4 * 4;
            const float* w1 = w0 + 320;
            v0 += a0[k] * w0[0] + a1[k] * w1[0];
            v1 += a0[k] * w0[1] + a1[k] * w1[1];
            v2 += a0[k] * w0[2] + a1[k] * w1[2];
            v3 += a0[k] * w0[3] + a1[k] * w1[3];
        }
        half4 o;
        o[0] = (_Float16)fmaxf(v0, 0.f); o[1] = (_Float16)fmaxf(v1, 0.f);
        o[2] = (_Float16)fmaxf(v2, 0.f); o[3] = (_Float16)fmaxf(v3, 0.f);
        *reinterpret_cast<half4*>(orow + f4 * 4) = o;
    }
}

// ---------------- split aggregate-X (fp16 node-major src), 2-edge unroll ---
template <int TPN>
__global__ __launch_bounds__(256, 3)
void k_aggx(const _Float16* __restrict__ xp, const int* __restrict__ off,
            const int* __restrict__ csrc, const float* __restrict__ gw,
            const float* __restrict__ inv, _Float16* __restrict__ agg, int N) {
    constexpr int CIN = TPN * 4;
    constexpr int KDT = KK * CIN / 32;
    int tid = threadIdx.x;
    int nl = tid / TPN, tt = tid - nl * TPN;
    int node = blockIdx.x * (256 / TPN) + nl;
    if (node >= N) return;
    float a[KK][4];
#pragma unroll
    for (int k = 0; k < KK; ++k)
#pragma unroll
        for (int e = 0; e < 4; ++e) a[k][e] = 0.f;
    int j0 = off[node], j1 = off[node + 1];
    int j = j0;
    for (; j + 1 < j1; j += 2) {
        int sa = csrc[j];
        int sb = csrc[j + 1];
        LOAD_G(gw, j, Ga)
        LOAD_G(gw, j + 1, Gb)
        half4 ha = *reinterpret_cast<const half4*>(xp + (size_t)sa * CIN + 4 * tt);
        half4 hb = *reinterpret_cast<const half4*>(xp + (size_t)sb * CIN + 4 * tt);
        float a0 = ha[0], a1 = ha[1], a2 = ha[2], a3 = ha[3];
        float b0 = hb[0], b1 = hb[1], b2 = hb[2], b3 = hb[3];
#pragma unroll
        for (int k = 0; k < KK; ++k) {
            a[k][0] = fmaf(Ga[k], a0, a[k][0]);
            a[k][1] = fmaf(Ga[k], a1, a[k][1]);
            a[k][2] = fmaf(Ga[k], a2, a[k][2]);
            a[k][3] = fmaf(Ga[k], a3, a[k][3]);
            a[k][0] = fmaf(Gb[k], b0, a[k][0]);
            a[k][1] = fmaf(Gb[k], b1, a[k][1]);
            a[k][2] = fmaf(Gb[k], b2, a[k][2]);
            a[k][3] = fmaf(Gb[k], b3, a[k][3]);
        }
    }
    if (j < j1) {
        int sa = csrc[j];
        LOAD_G(gw, j, Ga)
        half4 ha = *reinterpret_cast<const half4*>(xp + (size_t)sa * CIN + 4 * tt);
        float a0 = ha[0], a1 = ha[1], a2 = ha[2], a3 = ha[3];
#pragma unroll
        for (int k = 0; k < KK; ++k) {
            a[k][0] = fmaf(Ga[k], a0, a[k][0]);
            a[k][1] = fmaf(Ga[k], a1, a[k][1]);
            a[k][2] = fmaf(Ga[k], a2, a[k][2]);
            a[k][3] = fmaf(Ga[k], a3, a[k][3]);
        }
    }
    float iv = inv[node];
#pragma unroll
    for (int k = 0; k < KK; ++k) {
        half4 o;
        o[0] = (_Float16)(a[k][0] * iv); o[1] = (_Float16)(a[k][1] * iv);
        o[2] = (_Float16)(a[k][2] * iv); o[3] = (_Float16)(a[k][3] * iv);
        int kd = k * CIN + 4 * tt;
        *reinterpret_cast<half4*>(agg + fragi(node, kd, KDT) * 8 + (kd & 7)) = o;
    }
}

// ---------------- L4/L5 aggregate v7: csrc lane-preload + readlane --------
// WPB waves/block, NPW nodes/wave (WPB*NPW == 16 -> one fragment m-tile).
// Per node: one coalesced load fetches the whole csrc window into lanes;
// per-edge indices resolve via readlane (no memory latency in the chain).
template <int CA, int CB, int WPB, int NPW>
__global__ __launch_bounds__(WPB * 64)
void k_aggf3(const _Float16* __restrict__ xA, const _Float16* __restrict__ xB,
             const int* __restrict__ off, const int* __restrict__ csrc,
             const float* __restrict__ gw, const float* __restrict__ inv,
             _Float16* __restrict__ agg, int nodeBase) {
    constexpr int CIN = CA + CB;
    constexpr int PAIRS = CIN / 2;
    constexpr int P = (PAIRS + 63) / 64;
    constexpr int KDT = KK * CIN / 32;
    constexpr int STRIDE = KK * CIN + 8;
    __shared__ _Float16 lds[16 * STRIDE];
    const int lane = threadIdx.x & 63;
    const int wv = threadIdx.x >> 6;
#pragma unroll
    for (int u = 0; u < NPW; ++u) {
        const int nl = wv * NPW + u;
        const int node = __builtin_amdgcn_readfirstlane(nodeBase + blockIdx.x * 16 + nl);
        float a[KK][2 * P];
#pragma unroll
        for (int k = 0; k < KK; ++k)
#pragma unroll
            for (int p = 0; p < 2 * P; ++p) a[k][p] = 0.f;
        int j0 = __builtin_amdgcn_readfirstlane(off[node]);
        int j1 = __builtin_amdgcn_readfirstlane(off[node + 1]);
        int deg = j1 - j0;
        if (deg > 0) {
            int pl = j0 + (lane < deg ? lane : deg - 1);
            int sall = csrc[pl];                    // one coalesced window load
            int e = 0;
            for (; e + 1 < deg; e += 2) {
                int sa = __builtin_amdgcn_readlane(sall, e);
                int sb = __builtin_amdgcn_readlane(sall, e + 1);
                LOAD_G(gw, j0 + e, Ga)
                LOAD_G(gw, j0 + e + 1, Gb)
                float xa0[P], xa1[P], xb0[P], xb1[P];
#pragma unroll
                for (int p = 0; p < P; ++p) {
                    int c0 = 2 * (lane + 64 * p);
                    xa0[p] = 0.f; xa1[p] = 0.f; xb0[p] = 0.f; xb1[p] = 0.f;
                    if (c0 < CIN) {
                        const _Float16* qa = (c0 < CA) ? (xA + (size_t)(sa >> 3) * CA + c0)
                                                       : (xB + (size_t)sa * CB + (c0 - CA));
                        const _Float16* qb = (c0 < CA) ? (xA + (size_t)(sb >> 3) * CA + c0)
                                                       : (xB + (size_t)sb * CB + (c0 - CA));
                        half2t ha = *reinterpret_cast<const half2t*>(qa);
                        half2t hb = *reinterpret_cast<const half2t*>(qb);
                        xa0[p] = ha[0]; xa1[p] = ha[1];
                        xb0[p] = hb[0]; xb1[p] = hb[1];
                    }
                }
#pragma unroll
                for (int k = 0; k < KK; ++k)
#pragma unroll
                    for (int p = 0; p < P; ++p) {
                        a[k][2 * p] = fmaf(Ga[k], xa0[p], a[k][2 * p]);
                        a[k][2 * p + 1] = fmaf(Ga[k], xa1[p], a[k][2 * p + 1]);
                        a[k][2 * p] = fmaf(Gb[k], xb0[p], a[k][2 * p]);
                        a[k][2 * p + 1] = fmaf(Gb[k], xb1[p], a[k][2 * p + 1]);
                    }
            }
            if (e < deg) {
                int sa = __builtin_amdgcn_readlane(sall, e);
                LOAD_G(gw, j0 + e, Ga)
                float xa0[P], xa1[P];
#pragma unroll
                for (int p = 0; p < P; ++p) {
                    int c0 = 2 * (lane + 64 * p);
                    xa0[p] = 0.f; xa1[p] = 0.f;
                    if (c0 < CIN) {
                        const _Float16* qa = (c0 < CA) ? (xA + (size_t)(sa >> 3) * CA + c0)
                                                       : (xB + (size_t)sa * CB + (c0 - CA));
                        half2t ha = *reinterpret_cast<const half2t*>(qa);
                        xa0[p] = ha[0]; xa1[p] = ha[1];
                    }
                }
#pragma unroll
                for (int k = 0; k < KK; ++k)
#pragma unroll
                    for (int p = 0; p < P; ++p) {
                        a[k][2 * p] = fmaf(Ga[k], xa0[p], a[k][2 * p]);
                        a[k][2 * p + 1] = fmaf(Ga[k], xa1[p], a[k][2 * p + 1]);
                    }
            }
        }
        float iv = inv[node];
#pragma unroll
        for (int k = 0; k < KK; ++k)
#pragma unroll
            for (int p = 0; p < P; ++p) {
                int c0 = 2 * (lane + 64 * p);
                if (c0 < CIN) {
                    half2t o;
                    o[0] = (_Float16)(a[k][2 * p] * iv);
                    o[1] = (_Float16)(a[k][2 * p + 1] * iv);
                    *reinterpret_cast<half2t*>(&lds[nl * STRIDE + k * CIN + c0]) = o;
                }
            }
    }
    __syncthreads();
    f16x8* ag = reinterpret_cast<f16x8*>(agg);
    for (int s = threadIdx.x; s < KDT * 64; s += WPB * 64) {
        int t = s >> 6, l = s & 63;
        int nd = l & 15, q = l >> 4;
        f16x8 v = *reinterpret_cast<const f16x8*>(&lds[nd * STRIDE + t * 32 + q * 8]);
        ag[((size_t)blockIdx.x * KDT + t) * 64 + l] = v;
    }
}

// ---------------- pipelined split-K MFMA GEMM (fragment-tile operands) -----
// OUTH: 0 = fp32 out, 1 = fp16 out (KS==1 path only).
template <int WB, int NT, int ITERS, int KS, int ACT, int FST, int OUTH>
__global__ __launch_bounds__(WB * 64)
void k_gemm2(const _Float16* __restrict__ A, const _Float16* __restrict__ B,
             const float* __restrict__ bias, void* __restrict__ outv, int M) {
    constexpr int KDT = KS * ITERS;
    constexpr int F = NT * 16;
    const int lane = threadIdx.x & 63;
    const int wv = threadIdx.x >> 6;
    const int lm = lane & 15;
    const int q = lane >> 4;
    const int ks = blockIdx.x;
    const int t0 = ks * ITERS;
    const size_t m0 = (size_t)blockIdx.y * (WB * 16) + wv * 16;
    const size_t mblk = m0 >> 4;
    f32x4 acc[NT];
#pragma unroll
    for (int t = 0; t < NT; ++t) acc[t] = (f32x4){0.f, 0.f, 0.f, 0.f};
    const f16x8* ap = (const f16x8*)A + (mblk * KDT + t0) * 64 + lane;
    const f16x8* bp = (const f16x8*)B + (size_t)t0 * 64 + lane;
    f16x8 af = ap[0];
    f16x8 bf[NT];
#pragma unroll
    for (int t = 0; t < NT; ++t) bf[t] = bp[(size_t)t * KDT * 64];
#pragma unroll
    for (int i = 0; i < ITERS; ++i) {
        f16x8 afn; f16x8 bfn[NT];
        if (i + 1 < ITERS) {
            afn = ap[(size_t)(i + 1) * 64];
#pragma unroll
            for (int t = 0; t < NT; ++t)
                bfn[t] = bp[((size_t)t * KDT + i + 1) * 64];
        }
#pragma unroll
        for (int t = 0; t < NT; ++t)
            acc[t] = __builtin_amdgcn_mfma_f32_16x16x32_f16(af, bf[t], acc[t], 0, 0, 0);
        af = afn;
#pragma unroll
        for (int t = 0; t < NT; ++t) bf[t] = bfn[t];
    }
    if (KS == 1) {
#pragma unroll
        for (int t = 0; t < NT; ++t) {
            int f = t * 16 + lm;
            if (f < FST) {
                float b = bias ? bias[f] : 0.0f;
#pragma unroll
                for (int r = 0; r < 4; ++r) {
                    float v = acc[t][r] + b;
                    v = (ACT == 1) ? tanhf(v) : fmaxf(v, 0.0f);
                    if (OUTH) ((_Float16*)outv)[(m0 + q * 4 + r) * (size_t)FST + f] = (_Float16)v;
                    else ((float*)outv)[(m0 + q * 4 + r) * (size_t)FST + f] = v;
                }
            }
        }
    } else {
        float* pout = (float*)outv + (size_t)ks * M * F;
#pragma unroll
        for (int t = 0; t < NT; ++t) {
            int f = t * 16 + lm;
#pragma unroll
            for (int r = 0; r < 4; ++r)
                pout[(m0 + q * 4 + r) * (size_t)F + f] = acc[t][r];
        }
    }
}

// reduce split-K partials: out[m][f<FST] = act(sum_s part[s][m][f] + bias)
template <int KS, int F, int FST, int ACT, int OUTH>
__global__ __launch_bounds__(256)
void k_redact(const float* __restrict__ part, const float* __restrict__ bias,
              void* __restrict__ outv, int M) {
    int i = blockIdx.x * 256 + threadIdx.x;
    if (i >= M * FST) return;
    int m = i / FST, f = i - m * FST;
    float v = 0.0f;
#pragma unroll
    for (int s = 0; s < KS; ++s) v += part[((size_t)s * M + m) * F + f];
    if (bias) v += bias[f];
    v = (ACT == 1) ? tanhf(v) : fmaxf(v, 0.0f);
    if (OUTH) ((_Float16*)outv)[(size_t)m * FST + f] = (_Float16)v;
    else ((float*)outv)[(size_t)m * FST + f] = v;
}

// out[j,f] = max over the 8 fine nodes of group j — fp16 in, fp16 out.
__global__ __launch_bounds__(256)
void k_pool8h(const _Float16* __restrict__ in, _Float16* __restrict__ out, int total, int F) {
    int i = blockIdx.x * 256 + threadIdx.x;
    if (i >= total) return;
    int j = i / F;
    int f = i - j * F;
    const _Float16* p = in + (size_t)(j << 3) * F + f;
    float m = (float)p[0];
#pragma unroll
    for (int r = 1; r < 8; ++r) m = fmaxf(m, (float)p[(size_t)r * F]);
    out[i] = (_Float16)m;
}

extern "C" void kernel_launch(void* const* d_in, const int* in_sizes, int n_in,
                              void* d_out, int out_size, void* d_ws, size_t ws_size,
                              hipStream_t stream) {
    const float* n_feat = (const float*)d_in[0];
    const int* src1 = (const int*)d_in[1];
    const int* dst1 = (const int*)d_in[2];
    const float* pkor1 = (const float*)d_in[3];
    const int* src2 = (const int*)d_in[4];
    const int* dst2 = (const int*)d_in[5];
    const float* pkor2 = (const float*)d_in[6];
    const int* src3 = (const int*)d_in[7];
    const int* dst3 = (const int*)d_in[8];
    const float* pkor3 = (const float*)d_in[9];
    const float* W1 = (const float*)d_in[16];
    const float* mu1 = (const float*)d_in[17];
    const float* is1 = (const float*)d_in[18];
    const float* b1 = (const float*)d_in[19];
    const float* W2 = (const float*)d_in[20];
    const float* mu2 = (const float*)d_in[21];
    const float* is2 = (const float*)d_in[22];
    const float* W3 = (const float*)d_in[23];
    const float* mu3 = (const float*)d_in[24];
    const float* is3 = (const float*)d_in[25];
    const float* W4 = (const float*)d_in[26];
    const float* mu4 = (const float*)d_in[27];
    const float* is4 = (const float*)d_in[28];
    const float* W5 = (const float*)d_in[29];
    const float* mu5 = (const float*)d_in[30];
    const float* is5 = (const float*)d_in[31];
    const float* b5 = (const float*)d_in[32];

    const int E1 = in_sizes[1], E2 = in_sizes[4], E3 = in_sizes[7];
    const int NT_ = N0C + N1C + N2C;

    char* w = (char*)d_ws;
    auto alloc = [&](size_t bytes) {
        void* p = (void*)w;
        w += (bytes + 255) & ~(size_t)255;
        return p;
    };
    int* degs = (int*)alloc((size_t)NT_ * 2 * 4);
    int* deg1 = degs, *deg2 = degs + N0C, *deg3 = degs + N0C + N1C;
    int* cur1 = degs + NT_, *cur2 = cur1 + N0C, *cur3 = cur2 + N1C;
    int* off1 = (int*)alloc(((size_t)N0C + 1) * 4);
    int* off2 = (int*)alloc(((size_t)N1C + 1) * 4);
    int* off3 = (int*)alloc(((size_t)N2C + 1) * 4);
    int* part = (int*)alloc(292 * 4);
    int* csrc1 = (int*)alloc((size_t)E1 * 4);
    float2* cpk1 = (float2*)alloc((size_t)E1 * 8);
    int* csrc2 = (int*)alloc((size_t)E2 * 4);
    float2* cpk2 = (float2*)alloc((size_t)E2 * 8);
    int* csrc3 = (int*)alloc((size_t)E3 * 4);
    float2* cpk3 = (float2*)alloc((size_t)E3 * 8);
    float* inv1 = (float*)alloc((size_t)N0C * 4);
    float* inv2 = (float*)alloc((size_t)N1C * 4);
    float* inv3 = (float*)alloc((size_t)N2C * 4);
    float* g1 = (float*)alloc(((size_t)2 * E1 + 2 * E2 + E3) * 12 * 4);
    float* g5 = g1 + (size_t)E1 * 12;
    float* g2 = g5 + (size_t)E1 * 12;
    float* g4 = g2 + (size_t)E2 * 12;
    float* g3 = g4 + (size_t)E2 * 12;
    _Float16* out0 = (_Float16*)alloc((size_t)N0C * 32 * 2);
    _Float16* out1 = (_Float16*)alloc((size_t)N1C * 64 * 2);
    _Float16* out2 = (_Float16*)alloc((size_t)N2C * 128 * 2);
    _Float16* out3 = (_Float16*)alloc((size_t)N1C * 64 * 2);
    _Float16* hp1 = (_Float16*)alloc((size_t)N1C * 32 * 2);
    _Float16* hp2 = (_Float16*)alloc((size_t)N2C * 64 * 2);
    _Float16* agg2 = (_Float16*)alloc((size_t)N1C * 320 * 2);
    _Float16* agg3 = (_Float16*)alloc((size_t)N2C * 640 * 2);
    _Float16* Wt2 = (_Float16*)alloc((size_t)64 * 320 * 2);
    _Float16* Wt3 = (_Float16*)alloc((size_t)128 * 640 * 2);
    _Float16* Wt4 = (_Float16*)alloc((size_t)64 * 1920 * 2);
    _Float16* Wt5 = (_Float16*)alloc((size_t)48 * 960 * 2);
    size_t used = (size_t)(w - (char*)d_ws);
    size_t rem = (ws_size > used) ? (ws_size - used) : 0;
    _Float16* agg4 = (_Float16*)w;
    float* part4 = (float*)(w + (((size_t)N1C * 1920 * 2 + 255) & ~(size_t)255));
    int npass = 1;
    while ((size_t)(N0C / npass) * 1920 > rem && npass < 16) npass <<= 1;
    const int chunk = N0C / npass;
    _Float16* agg5 = (_Float16*)w;

    const int ET = E1 + E2 + E3;
    const int GT = 2 * E1 + 2 * E2 + E3;

    // ---- CSR build (batched) + weight prep + gw precompute
    hipMemsetAsync(degs, 0, (size_t)NT_ * 2 * 4, stream);
    k_prep_wt<<<cdiv(271360, 256), 256, 0, stream>>>(W1, W2, W3, W4, W5,
                                                     Wt2, Wt3, Wt4, Wt5);
    k_hist3<<<cdiv(ET, 256), 256, 0, stream>>>(dst1, dst2, dst3, deg1, deg2, deg3, E1, E2, E3);
    k_scan1_3<<<292, 256, 0, stream>>>(deg1, off1, deg2, off2, deg3, off3, part);
    k_scan2_3<<<3, 256, 0, stream>>>(part);
    k_scan3_3<<<292, 256, 0, stream>>>(off1, off2, off3, part, deg1, deg2, deg3,
                                       inv1, inv2, inv3, E1, E2, E3);
    k_scatter3<<<cdiv(ET, 256), 256, 0, stream>>>(
        src1, dst1, pkor1, off1, cur1, csrc1, cpk1,
        src2, dst2, pkor2, off2, cur2, csrc2, cpk2,
        src3, dst3, pkor3, off3, cur3, csrc3, cpk3, E1, E2, E3);
    k_gw<<<cdiv(GT, 256), 256, 0, stream>>>(
        cpk1, cpk2, cpk3, mu1, is1, mu5, is5, mu2, is2, mu4, is4, mu3, is3,
        g1, g5, g2, g4, g3, E1, E2, E3);

    // ---- L1 fused: aggregate + mini-GEMM + b1 + relu -> out0 (N0,32) fp16
    k_l1<<<N0C / 256, 256, 0, stream>>>(n_feat, off1, csrc1, g1, inv1, W1, b1, out0);

    // ---- L2: pool -> aggX (Cin=32) -> agg2; GEMM+relu -> out1 (N1,64) fp16
    k_pool8h<<<cdiv(N1C * 32, 256), 256, 0, stream>>>(out0, hp1, N1C * 32, 32);
    k_aggx<8><<<cdiv(N1C, 32), 256, 0, stream>>>(hp1, off2, csrc2, g2, inv2, agg2, N1C);
    k_gemm2<2, 4, 10, 1, 0, 64, 1><<<dim3(1, N1C / 32), 128, 0, stream>>>(agg2, Wt2, nullptr, out1, N1C);

    // ---- L3: pool -> aggX (Cin=64) -> agg3; GEMM+relu -> out2 (N2,128) fp16
    k_pool8h<<<cdiv(N2C * 64, 256), 256, 0, stream>>>(out1, hp2, N2C * 64, 64);
    k_aggx<16><<<cdiv(N2C, 16), 256, 0, stream>>>(hp2, off3, csrc3, g3, inv3, agg3, N2C);
    k_gemm2<1, 8, 20, 1, 0, 128, 1><<<dim3(1, N2C / 16), 64, 0, stream>>>(agg3, Wt3, nullptr, out2, N2C);

    // ---- L4: aggF v7 (16 waves x 1 node) -> agg4; split-K GEMM; reduce -> out3
    k_aggf3<128, 64, 16, 1><<<N1C / 16, 1024, 0, stream>>>(
        out2, out1, off2, csrc2, g4, inv2, agg4, 0);
    k_gemm2<2, 4, 15, 4, 0, 64, 0><<<dim3(4, N1C / 32), 128, 0, stream>>>(agg4, Wt4, nullptr, part4, N1C);
    k_redact<4, 64, 64, 0, 1><<<cdiv(N1C * 64, 256), 256, 0, stream>>>(part4, nullptr, out3, N1C);

    // ---- L5: aggF v7 (8 waves x 2 nodes) -> agg5 (chunked); fused GEMM
    //      (KS=1, ITERS=30, b5 + tanh) -> d_out fp32
    for (int p = 0; p < npass; ++p) {
        int base = p * chunk;
        k_aggf3<64, 32, 8, 2><<<chunk / 16, 512, 0, stream>>>(
            out3, out0, off1, csrc1, g5, inv1, agg5, base);
        k_gemm2<4, 3, 30, 1, 1, 40, 0><<<dim3(1, chunk / 64), 256, 0, stream>>>(
            agg5, Wt5, b5, ((float*)d_out) + (size_t)base * 40, chunk);
    }
}

// Round 17
// 304.174 us; speedup vs baseline: 1.2693x; 1.1306x over previous
//
#include <hip/hip_runtime.h>

// ---------------------------------------------------------------------------
// UNet_old (graph U-Net, GMMConv K=10) on MI355X. fp32 in / fp32 out.
// R17: k_aggf4 — GEMM fused into the aggregation block. The 16-node agg tile
// already sits in LDS in A-fragment order; after the existing syncthreads,
// NT waves run the full-K MFMA chain for one n-tile each (Wt from L2,
// 1-deep prefetch) and write the activated output directly. Deletes the
// agg5 252MB and agg4 63MB round-trips, part4, both tail GEMM dispatches,
// redact, and all workspace chunking. LDS unchanged (<=62KB) -> same
// occupancy as R16's aggf3. Rest identical to R16.
// ---------------------------------------------------------------------------

#define N0C 65536
#define N1C 8192
#define N2C 1024
#define KK 10

typedef _Float16 half2t __attribute__((ext_vector_type(2)));
typedef _Float16 half4 __attribute__((ext_vector_type(4)));
typedef _Float16 f16x8 __attribute__((ext_vector_type(8)));
typedef float f32x4 __attribute__((ext_vector_type(4)));

static inline int cdiv(long long a, long long b) { return (int)((a + b - 1) / b); }

// fragment-tile index (in f16x8 units) for matrix row r, k-index kd.
__device__ __forceinline__ size_t fragi(int r, int kd, int KDT) {
    return ((size_t)(r >> 4) * KDT + (kd >> 5)) * 64 + ((kd >> 3) & 3) * 16 + (r & 15);
}

// ---------------- batched CSR build (3 graphs) ----------------

__global__ __launch_bounds__(256)
void k_hist3(const int* __restrict__ d1, const int* __restrict__ d2,
             const int* __restrict__ d3, int* __restrict__ g1,
             int* __restrict__ g2, int* __restrict__ g3,
             int E1, int E2, int E3) {
    int i = blockIdx.x * 256 + threadIdx.x;
    if (i < E1) atomicAdd(&g1[d1[i]], 1);
    else if (i < E1 + E2) atomicAdd(&g2[d2[i - E1]], 1);
    else if (i < E1 + E2 + E3) atomicAdd(&g3[d3[i - E1 - E2]], 1);
}

__device__ __forceinline__ void map_graph(int b, int& lb, int& gi) {
    if (b < 256) { gi = 0; lb = b; }
    else if (b < 288) { gi = 1; lb = b - 256; }
    else { gi = 2; lb = b - 288; }
}

__global__ __launch_bounds__(256)
void k_scan1_3(const int* __restrict__ deg1, int* __restrict__ off1,
               const int* __restrict__ deg2, int* __restrict__ off2,
               const int* __restrict__ deg3, int* __restrict__ off3,
               int* __restrict__ part) {
    __shared__ int s[256];
    int lb, gi; map_graph(blockIdx.x, lb, gi);
    const int* deg = gi == 0 ? deg1 : (gi == 1 ? deg2 : deg3);
    int* off = gi == 0 ? off1 : (gi == 1 ? off2 : off3);
    int* prt = part + (gi == 0 ? 0 : (gi == 1 ? 256 : 288));
    int i = lb * 256 + threadIdx.x;
    int v = deg[i];
    s[threadIdx.x] = v;
    __syncthreads();
#pragma unroll
    for (int d = 1; d < 256; d <<= 1) {
        int t = (threadIdx.x >= d) ? s[threadIdx.x - d] : 0;
        __syncthreads();
        s[threadIdx.x] += t;
        __syncthreads();
    }
    off[i] = s[threadIdx.x] - v;
    if (threadIdx.x == 255) prt[lb] = s[255];
}

__global__ __launch_bounds__(256)
void k_scan2_3(int* __restrict__ part) {
    __shared__ int s[256];
    int nb = blockIdx.x == 0 ? 256 : (blockIdx.x == 1 ? 32 : 4);
    int* p = part + (blockIdx.x == 0 ? 0 : (blockIdx.x == 1 ? 256 : 288));
    int v = (threadIdx.x < nb) ? p[threadIdx.x] : 0;
    s[threadIdx.x] = v;
    __syncthreads();
#pragma unroll
    for (int d = 1; d < 256; d <<= 1) {
        int t = (threadIdx.x >= d) ? s[threadIdx.x - d] : 0;
        __syncthreads();
        s[threadIdx.x] += t;
        __syncthreads();
    }
    if (threadIdx.x < nb) p[threadIdx.x] = s[threadIdx.x] - v;
}

__global__ __launch_bounds__(256)
void k_scan3_3(int* __restrict__ off1, int* __restrict__ off2, int* __restrict__ off3,
               const int* __restrict__ part,
               const int* __restrict__ deg1, const int* __restrict__ deg2,
               const int* __restrict__ deg3,
               float* __restrict__ inv1, float* __restrict__ inv2,
               float* __restrict__ inv3, int E1, int E2, int E3) {
    int lb, gi; map_graph(blockIdx.x, lb, gi);
    int* off = gi == 0 ? off1 : (gi == 1 ? off2 : off3);
    const int* deg = gi == 0 ? deg1 : (gi == 1 ? deg2 : deg3);
    float* inv = gi == 0 ? inv1 : (gi == 1 ? inv2 : inv3);
    const int* prt = part + (gi == 0 ? 0 : (gi == 1 ? 256 : 288));
    int n = gi == 0 ? N0C : (gi == 1 ? N1C : N2C);
    int E = gi == 0 ? E1 : (gi == 1 ? E2 : E3);
    int i = lb * 256 + threadIdx.x;
    off[i] += prt[lb];
    inv[i] = 1.0f / fmaxf((float)deg[i], 1.0f);
    if (i == n - 1) off[n] = E;
}

__global__ __launch_bounds__(256)
void k_scatter3(const int* __restrict__ s1, const int* __restrict__ d1,
                const float* __restrict__ p1, const int* __restrict__ o1,
                int* __restrict__ c1, int* __restrict__ cs1, float2* __restrict__ cp1,
                const int* __restrict__ s2, const int* __restrict__ d2,
                const float* __restrict__ p2, const int* __restrict__ o2,
                int* __restrict__ c2, int* __restrict__ cs2, float2* __restrict__ cp2,
                const int* __restrict__ s3, const int* __restrict__ d3,
                const float* __restrict__ p3, const int* __restrict__ o3,
                int* __restrict__ c3, int* __restrict__ cs3, float2* __restrict__ cp3,
                int E1, int E2, int E3) {
    int i = blockIdx.x * 256 + threadIdx.x;
    const int* src; const int* dst; const float* pk; const int* off;
    int* cur; int* csrc; float2* cpk; int e;
    if (i < E1) { src = s1; dst = d1; pk = p1; off = o1; cur = c1; csrc = cs1; cpk = cp1; e = i; }
    else if (i < E1 + E2) { src = s2; dst = d2; pk = p2; off = o2; cur = c2; csrc = cs2; cpk = cp2; e = i - E1; }
    else if (i < E1 + E2 + E3) { src = s3; dst = d3; pk = p3; off = o3; cur = c3; csrc = cs3; cpk = cp3; e = i - E1 - E2; }
    else return;
    int d = dst[e];
    int p = off[d] + atomicAdd(&cur[d], 1);
    csrc[p] = src[e];
    cpk[p] = reinterpret_cast<const float2*>(pk)[e];
}

// ---------------- batched gw precompute (5 layer-graph pairs) --------------
__global__ __launch_bounds__(256)
void k_gw(const float2* __restrict__ cp1, const float2* __restrict__ cp2,
          const float2* __restrict__ cp3,
          const float* __restrict__ mu1, const float* __restrict__ is1,
          const float* __restrict__ mu5, const float* __restrict__ is5,
          const float* __restrict__ mu2, const float* __restrict__ is2,
          const float* __restrict__ mu4, const float* __restrict__ is4,
          const float* __restrict__ mu3, const float* __restrict__ is3,
          float* __restrict__ g1, float* __restrict__ g5, float* __restrict__ g2,
          float* __restrict__ g4, float* __restrict__ g3,
          int E1, int E2, int E3) {
    int i = blockIdx.x * 256 + threadIdx.x;
    const float2* cp; const float* mu; const float* isg; float* g; int e;
    if (i < E1) { cp = cp1; mu = mu1; isg = is1; g = g1; e = i; }
    else if (i < 2 * E1) { cp = cp1; mu = mu5; isg = is5; g = g5; e = i - E1; }
    else if (i < 2 * E1 + E2) { cp = cp2; mu = mu2; isg = is2; g = g2; e = i - 2 * E1; }
    else if (i < 2 * E1 + 2 * E2) { cp = cp2; mu = mu4; isg = is4; g = g4; e = i - 2 * E1 - E2; }
    else if (i < 2 * E1 + 2 * E2 + E3) { cp = cp3; mu = mu3; isg = is3; g = g3; e = i - 2 * E1 - 2 * E2; }
    else return;
    float2 pk = cp[e];
    float o[KK];
#pragma unroll
    for (int k = 0; k < KK; ++k) {
        float dx = (pk.x - mu[2 * k]) * isg[2 * k];
        float dy = (pk.y - mu[2 * k + 1]) * isg[2 * k + 1];
        o[k] = __expf(-0.5f * (dx * dx + dy * dy));
    }
    float4* gp = reinterpret_cast<float4*>(g + (size_t)e * 12);
    gp[0] = make_float4(o[0], o[1], o[2], o[3]);
    gp[1] = make_float4(o[4], o[5], o[6], o[7]);
    gp[2] = make_float4(o[8], o[9], 0.f, 0.f);
}

#define LOAD_G(gw, j, G)                                                     \
    float G[KK];                                                             \
    {                                                                        \
        const float4* gp_ = reinterpret_cast<const float4*>((gw) + (size_t)(j) * 12); \
        float4 g0_ = gp_[0], g1_ = gp_[1]; float2 g2_ = *reinterpret_cast<const float2*>(gp_ + 2); \
        G[0] = g0_.x; G[1] = g0_.y; G[2] = g0_.z; G[3] = g0_.w;              \
        G[4] = g1_.x; G[5] = g1_.y; G[6] = g1_.z; G[7] = g1_.w;              \
        G[8] = g2_.x; G[9] = g2_.y;                                          \
    }

// ---------------- batched weight prep -> B-fragment tiles ----------------
__global__ __launch_bounds__(256)
void k_prep_wt(const float* __restrict__ W1, const float* __restrict__ W2,
               const float* __restrict__ W3, const float* __restrict__ W4,
               const float* __restrict__ W5,
               _Float16* __restrict__ T2,
               _Float16* __restrict__ T3, _Float16* __restrict__ T4,
               _Float16* __restrict__ T5) {
    int id = blockIdx.x * 256 + threadIdx.x;
    if (id < 20480) {                      // Wt2: F=64, KD=320 (Cin=32)
        int f = id / 320, kc = id % 320;
        T2[fragi(f, kc, 10) * 8 + (kc & 7)] = (_Float16)W2[(kc % 32) * 640 + (kc / 32) * 64 + f];
        return;
    }
    id -= 20480;
    if (id < 81920) {                      // Wt3: F=128, KD=640 (Cin=64)
        int f = id / 640, kc = id % 640;
        T3[fragi(f, kc, 20) * 8 + (kc & 7)] = (_Float16)W3[(kc % 64) * 1280 + (kc / 64) * 128 + f];
        return;
    }
    id -= 81920;
    if (id < 122880) {                     // Wt4: F=64, KD=1920 (Cin=192)
        int f = id / 1920, kc = id % 1920;
        T4[fragi(f, kc, 60) * 8 + (kc & 7)] = (_Float16)W4[(kc % 192) * 640 + (kc / 192) * 64 + f];
        return;
    }
    id -= 122880;
    if (id < 46080) {                      // Wt5: F=48 (store 40), KD=960 (Cin=96)
        int f = id / 960, kc = id % 960;
        float v = (f < 40) ? W5[(kc % 96) * 400 + (kc / 96) * 40 + f] : 0.0f;
        T5[fragi(f, kc, 30) * 8 + (kc & 7)] = (_Float16)v;
    }
}

// ---------------- L1 fused: aggregate (Cin=2) + mini-GEMM + bias + relu ----
__global__ __launch_bounds__(256, 3)
void k_l1(const float* __restrict__ x, const int* __restrict__ off,
          const int* __restrict__ csrc, const float* __restrict__ gw,
          const float* __restrict__ inv, const float* __restrict__ W1,
          const float* __restrict__ b1, _Float16* __restrict__ out0) {
    __shared__ float Ws[640];
    __shared__ float bs[32];
    for (int i = threadIdx.x; i < 640; i += 256) Ws[i] = W1[i];
    if (threadIdx.x < 32) bs[threadIdx.x] = b1[threadIdx.x];
    __syncthreads();
    int n = blockIdx.x * 256 + threadIdx.x;
    float a0[KK], a1[KK];
#pragma unroll
    for (int k = 0; k < KK; ++k) { a0[k] = 0.f; a1[k] = 0.f; }
    int j0 = off[n], j1 = off[n + 1];
    int j = j0;
    for (; j + 1 < j1; j += 2) {
        int sa = csrc[j];
        int sb = csrc[j + 1];
        LOAD_G(gw, j, Ga)
        LOAD_G(gw, j + 1, Gb)
        float2 xa = reinterpret_cast<const float2*>(x)[sa];
        float2 xb = reinterpret_cast<const float2*>(x)[sb];
#pragma unroll
        for (int k = 0; k < KK; ++k) {
            a0[k] = fmaf(Ga[k], xa.x, a0[k]);
            a1[k] = fmaf(Ga[k], xa.y, a1[k]);
            a0[k] = fmaf(Gb[k], xb.x, a0[k]);
            a1[k] = fmaf(Gb[k], xb.y, a1[k]);
        }
    }
    if (j < j1) {
        int sa = csrc[j];
        LOAD_G(gw, j, Ga)
        float2 xa = reinterpret_cast<const float2*>(x)[sa];
#pragma unroll
        for (int k = 0; k < KK; ++k) {
            a0[k] = fmaf(Ga[k], xa.x, a0[k]);
            a1[k] = fmaf(Ga[k], xa.y, a1[k]);
        }
    }
    float iv = inv[n];
#pragma unroll
    for (int k = 0; k < KK; ++k) { a0[k] *= iv; a1[k] *= iv; }
    _Float16* orow = out0 + (size_t)n * 32;
#pragma unroll
    for (int f4 = 0; f4 < 8; ++f4) {
        float v0 = bs[f4 * 4], v1 = bs[f4 * 4 + 1], v2 = bs[f4 * 4 + 2], v3 = bs[f4 * 4 + 3];
#pragma unroll
        for (int k = 0; k < KK; ++k) {
            const float* w0 = Ws + k * 32 + f4 * 4;
            const float* w1 = w0 + 320;
            v0 += a0[k] * w0[0] + a1[k] * w1[0];
            v1 += a0[k] * w0[1] + a1[k] * w1[1];
            v2 += a0[k] * w0[2] + a1[k] * w1[2];
            v3 += a0[k] * w0[3] + a1[k] * w1[3];
        }
        half4 o;
        o[0] = (_Float16)fmaxf(v0, 0.f); o[1] = (_Float16)fmaxf(v1, 0.f);
        o[2] = (_Float16)fmaxf(v2, 0.f); o[3] = (_Float16)fmaxf(v3, 0.f);
        *reinterpret_cast<half4*>(orow + f4 * 4) = o;
    }
}

// ---------------- split aggregate-X (fp16 node-major src), 2-edge unroll ---
template <int TPN>
__global__ __launch_bounds__(256, 3)
void k_aggx(const _Float16* __restrict__ xp, const int* __restrict__ off,
            const int* __restrict__ csrc, const float* __restrict__ gw,
            const float* __restrict__ inv, _Float16* __restrict__ agg, int N) {
    constexpr int CIN = TPN * 4;
    constexpr int KDT = KK * CIN / 32;
    int tid = threadIdx.x;
    int nl = tid / TPN, tt = tid - nl * TPN;
    int node = blockIdx.x * (256 / TPN) + nl;
    if (node >= N) return;
    float a[KK][4];
#pragma unroll
    for (int k = 0; k < KK; ++k)
#pragma unroll
        for (int e = 0; e < 4; ++e) a[k][e] = 0.f;
    int j0 = off[node], j1 = off[node + 1];
    int j = j0;
    for (; j + 1 < j1; j += 2) {
        int sa = csrc[j];
        int sb = csrc[j + 1];
        LOAD_G(gw, j, Ga)
        LOAD_G(gw, j + 1, Gb)
        half4 ha = *reinterpret_cast<const half4*>(xp + (size_t)sa * CIN + 4 * tt);
        half4 hb = *reinterpret_cast<const half4*>(xp + (size_t)sb * CIN + 4 * tt);
        float a0 = ha[0], a1 = ha[1], a2 = ha[2], a3 = ha[3];
        float b0 = hb[0], b1 = hb[1], b2 = hb[2], b3 = hb[3];
#pragma unroll
        for (int k = 0; k < KK; ++k) {
            a[k][0] = fmaf(Ga[k], a0, a[k][0]);
            a[k][1] = fmaf(Ga[k], a1, a[k][1]);
            a[k][2] = fmaf(Ga[k], a2, a[k][2]);
            a[k][3] = fmaf(Ga[k], a3, a[k][3]);
            a[k][0] = fmaf(Gb[k], b0, a[k][0]);
            a[k][1] = fmaf(Gb[k], b1, a[k][1]);
            a[k][2] = fmaf(Gb[k], b2, a[k][2]);
            a[k][3] = fmaf(Gb[k], b3, a[k][3]);
        }
    }
    if (j < j1) {
        int sa = csrc[j];
        LOAD_G(gw, j, Ga)
        half4 ha = *reinterpret_cast<const half4*>(xp + (size_t)sa * CIN + 4 * tt);
        float a0 = ha[0], a1 = ha[1], a2 = ha[2], a3 = ha[3];
#pragma unroll
        for (int k = 0; k < KK; ++k) {
            a[k][0] = fmaf(Ga[k], a0, a[k][0]);
            a[k][1] = fmaf(Ga[k], a1, a[k][1]);
            a[k][2] = fmaf(Ga[k], a2, a[k][2]);
            a[k][3] = fmaf(Ga[k], a3, a[k][3]);
        }
    }
    float iv = inv[node];
#pragma unroll
    for (int k = 0; k < KK; ++k) {
        half4 o;
        o[0] = (_Float16)(a[k][0] * iv); o[1] = (_Float16)(a[k][1] * iv);
        o[2] = (_Float16)(a[k][2] * iv); o[3] = (_Float16)(a[k][3] * iv);
        int kd = k * CIN + 4 * tt;
        *reinterpret_cast<half4*>(agg + fragi(node, kd, KDT) * 8 + (kd & 7)) = o;
    }
}

// ---------------- L4/L5 fused aggregate + MFMA + act (k_aggf4) ------------
// Phase 1 (= aggf3): wave-per-node gather with csrc lane-preload + readlane,
// accumulators -> LDS in A-fragment row order (16 nodes = one m-tile).
// Phase 2: waves wv<NT each run the full-KDT MFMA chain for n-tile wv
// (A from LDS ds_read_b128, B from L2-resident Wt with 1-deep prefetch),
// then write act(acc+bias) straight to the output. No agg round-trip.
template <int CA, int CB, int WPB, int NPW, int NT, int ACT, int FST, int OUTH>
__global__ __launch_bounds__(WPB * 64)
void k_aggf4(const _Float16* __restrict__ xA, const _Float16* __restrict__ xB,
             const int* __restrict__ off, const int* __restrict__ csrc,
             const float* __restrict__ gw, const float* __restrict__ inv,
             const _Float16* __restrict__ Wt, const float* __restrict__ bias,
             void* __restrict__ outv, int nodeBase) {
    constexpr int CIN = CA + CB;
    constexpr int PAIRS = CIN / 2;
    constexpr int P = (PAIRS + 63) / 64;
    constexpr int KDT = KK * CIN / 32;
    constexpr int STRIDE = KK * CIN + 8;
    __shared__ _Float16 lds[16 * STRIDE];
    const int lane = threadIdx.x & 63;
    const int wv = threadIdx.x >> 6;
#pragma unroll
    for (int u = 0; u < NPW; ++u) {
        const int nl = wv * NPW + u;
        const int node = __builtin_amdgcn_readfirstlane(nodeBase + blockIdx.x * 16 + nl);
        float a[KK][2 * P];
#pragma unroll
        for (int k = 0; k < KK; ++k)
#pragma unroll
            for (int p = 0; p < 2 * P; ++p) a[k][p] = 0.f;
        int j0 = __builtin_amdgcn_readfirstlane(off[node]);
        int j1 = __builtin_amdgcn_readfirstlane(off[node + 1]);
        int deg = j1 - j0;
        if (deg > 0) {
            int pl = j0 + (lane < deg ? lane : deg - 1);
            int sall = csrc[pl];
            int e = 0;
            for (; e + 1 < deg; e += 2) {
                int sa = __builtin_amdgcn_readlane(sall, e);
                int sb = __builtin_amdgcn_readlane(sall, e + 1);
                LOAD_G(gw, j0 + e, Ga)
                LOAD_G(gw, j0 + e + 1, Gb)
                float xa0[P], xa1[P], xb0[P], xb1[P];
#pragma unroll
                for (int p = 0; p < P; ++p) {
                    int c0 = 2 * (lane + 64 * p);
                    xa0[p] = 0.f; xa1[p] = 0.f; xb0[p] = 0.f; xb1[p] = 0.f;
                    if (c0 < CIN) {
                        const _Float16* qa = (c0 < CA) ? (xA + (size_t)(sa >> 3) * CA + c0)
                                                       : (xB + (size_t)sa * CB + (c0 - CA));
                        const _Float16* qb = (c0 < CA) ? (xA + (size_t)(sb >> 3) * CA + c0)
                                                       : (xB + (size_t)sb * CB + (c0 - CA));
                        half2t ha = *reinterpret_cast<const half2t*>(qa);
                        half2t hb = *reinterpret_cast<const half2t*>(qb);
                        xa0[p] = ha[0]; xa1[p] = ha[1];
                        xb0[p] = hb[0]; xb1[p] = hb[1];
                    }
                }
#pragma unroll
                for (int k = 0; k < KK; ++k)
#pragma unroll
                    for (int p = 0; p < P; ++p) {
                        a[k][2 * p] = fmaf(Ga[k], xa0[p], a[k][2 * p]);
                        a[k][2 * p + 1] = fmaf(Ga[k], xa1[p], a[k][2 * p + 1]);
                        a[k][2 * p] = fmaf(Gb[k], xb0[p], a[k][2 * p]);
                        a[k][2 * p + 1] = fmaf(Gb[k], xb1[p], a[k][2 * p + 1]);
                    }
            }
            if (e < deg) {
                int sa = __builtin_amdgcn_readlane(sall, e);
                LOAD_G(gw, j0 + e, Ga)
                float xa0[P], xa1[P];
#pragma unroll
                for (int p = 0; p < P; ++p) {
                    int c0 = 2 * (lane + 64 * p);
                    xa0[p] = 0.f; xa1[p] = 0.f;
                    if (c0 < CIN) {
                        const _Float16* qa = (c0 < CA) ? (xA + (size_t)(sa >> 3) * CA + c0)
                                                       : (xB + (size_t)sa * CB + (c0 - CA));
                        half2t ha = *reinterpret_cast<const half2t*>(qa);
                        xa0[p] = ha[0]; xa1[p] = ha[1];
                    }
                }
#pragma unroll
                for (int k = 0; k < KK; ++k)
#pragma unroll
                    for (int p = 0; p < P; ++p) {
                        a[k][2 * p] = fmaf(Ga[k], xa0[p], a[k][2 * p]);
                        a[k][2 * p + 1] = fmaf(Ga[k], xa1[p], a[k][2 * p + 1]);
                    }
            }
        }
        float iv = inv[node];
#pragma unroll
        for (int k = 0; k < KK; ++k)
#pragma unroll
            for (int p = 0; p < P; ++p) {
                int c0 = 2 * (lane + 64 * p);
                if (c0 < CIN) {
                    half2t o;
                    o[0] = (_Float16)(a[k][2 * p] * iv);
                    o[1] = (_Float16)(a[k][2 * p + 1] * iv);
                    *reinterpret_cast<half2t*>(&lds[nl * STRIDE + k * CIN + c0]) = o;
                }
            }
    }
    __syncthreads();
    // ---- phase 2: MFMA n-tile per wave (wv < NT), full KDT chain
    if (wv < NT) {
        const int lm = lane & 15;
        const int q = lane >> 4;
        f32x4 acc = (f32x4){0.f, 0.f, 0.f, 0.f};
        const f16x8* bp = (const f16x8*)Wt + (size_t)wv * KDT * 64 + lane;
        f16x8 af = *reinterpret_cast<const f16x8*>(&lds[lm * STRIDE + q * 8]);
        f16x8 bf = bp[0];
#pragma unroll
        for (int i = 0; i < KDT; ++i) {
            f16x8 afn, bfn;
            if (i + 1 < KDT) {
                afn = *reinterpret_cast<const f16x8*>(&lds[lm * STRIDE + (i + 1) * 32 + q * 8]);
                bfn = bp[(size_t)(i + 1) * 64];
            }
            acc = __builtin_amdgcn_mfma_f32_16x16x32_f16(af, bf, acc, 0, 0, 0);
            af = afn; bf = bfn;
        }
        int f = wv * 16 + lm;
        if (f < FST) {
            float b = bias ? bias[f] : 0.0f;
#pragma unroll
            for (int r = 0; r < 4; ++r) {
                size_t node = (size_t)nodeBase + (size_t)blockIdx.x * 16 + q * 4 + r;
                float v = acc[r] + b;
                v = (ACT == 1) ? tanhf(v) : fmaxf(v, 0.0f);
                if (OUTH) ((_Float16*)outv)[node * FST + f] = (_Float16)v;
                else ((float*)outv)[node * FST + f] = v;
            }
        }
    }
}

// ---------------- pipelined MFMA GEMM (fragment-tile operands, L2/L3) ------
template <int WB, int NT, int ITERS, int ACT, int FST, int OUTH>
__global__ __launch_bounds__(WB * 64)
void k_gemm2(const _Float16* __restrict__ A, const _Float16* __restrict__ B,
             const float* __restrict__ bias, void* __restrict__ outv, int M) {
    constexpr int KDT = ITERS;
    const int lane = threadIdx.x & 63;
    const int wv = threadIdx.x >> 6;
    const int lm = lane & 15;
    const int q = lane >> 4;
    const size_t m0 = (size_t)blockIdx.y * (WB * 16) + wv * 16;
    const size_t mblk = m0 >> 4;
    f32x4 acc[NT];
#pragma unroll
    for (int t = 0; t < NT; ++t) acc[t] = (f32x4){0.f, 0.f, 0.f, 0.f};
    const f16x8* ap = (const f16x8*)A + mblk * KDT * 64 + lane;
    const f16x8* bp = (const f16x8*)B + lane;
    f16x8 af = ap[0];
    f16x8 bf[NT];
#pragma unroll
    for (int t = 0; t < NT; ++t) bf[t] = bp[(size_t)t * KDT * 64];
#pragma unroll
    for (int i = 0; i < ITERS; ++i) {
        f16x8 afn; f16x8 bfn[NT];
        if (i + 1 < ITERS) {
            afn = ap[(size_t)(i + 1) * 64];
#pragma unroll
            for (int t = 0; t < NT; ++t)
                bfn[t] = bp[((size_t)t * KDT + i + 1) * 64];
        }
#pragma unroll
        for (int t = 0; t < NT; ++t)
            acc[t] = __builtin_amdgcn_mfma_f32_16x16x32_f16(af, bf[t], acc[t], 0, 0, 0);
        af = afn;
#pragma unroll
        for (int t = 0; t < NT; ++t) bf[t] = bfn[t];
    }
#pragma unroll
    for (int t = 0; t < NT; ++t) {
        int f = t * 16 + lm;
        if (f < FST) {
            float b = bias ? bias[f] : 0.0f;
#pragma unroll
            for (int r = 0; r < 4; ++r) {
                float v = acc[t][r] + b;
                v = (ACT == 1) ? tanhf(v) : fmaxf(v, 0.0f);
                if (OUTH) ((_Float16*)outv)[(m0 + q * 4 + r) * (size_t)FST + f] = (_Float16)v;
                else ((float*)outv)[(m0 + q * 4 + r) * (size_t)FST + f] = v;
            }
        }
    }
}

// out[j,f] = max over the 8 fine nodes of group j — fp16 in, fp16 out.
__global__ __launch_bounds__(256)
void k_pool8h(const _Float16* __restrict__ in, _Float16* __restrict__ out, int total, int F) {
    int i = blockIdx.x * 256 + threadIdx.x;
    if (i >= total) return;
    int j = i / F;
    int f = i - j * F;
    const _Float16* p = in + (size_t)(j << 3) * F + f;
    float m = (float)p[0];
#pragma unroll
    for (int r = 1; r < 8; ++r) m = fmaxf(m, (float)p[(size_t)r * F]);
    out[i] = (_Float16)m;
}

extern "C" void kernel_launch(void* const* d_in, const int* in_sizes, int n_in,
                              void* d_out, int out_size, void* d_ws, size_t ws_size,
                              hipStream_t stream) {
    const float* n_feat = (const float*)d_in[0];
    const int* src1 = (const int*)d_in[1];
    const int* dst1 = (const int*)d_in[2];
    const float* pkor1 = (const float*)d_in[3];
    const int* src2 = (const int*)d_in[4];
    const int* dst2 = (const int*)d_in[5];
    const float* pkor2 = (const float*)d_in[6];
    const int* src3 = (const int*)d_in[7];
    const int* dst3 = (const int*)d_in[8];
    const float* pkor3 = (const float*)d_in[9];
    const float* W1 = (const float*)d_in[16];
    const float* mu1 = (const float*)d_in[17];
    const float* is1 = (const float*)d_in[18];
    const float* b1 = (const float*)d_in[19];
    const float* W2 = (const float*)d_in[20];
    const float* mu2 = (const float*)d_in[21];
    const float* is2 = (const float*)d_in[22];
    const float* W3 = (const float*)d_in[23];
    const float* mu3 = (const float*)d_in[24];
    const float* is3 = (const float*)d_in[25];
    const float* W4 = (const float*)d_in[26];
    const float* mu4 = (const float*)d_in[27];
    const float* is4 = (const float*)d_in[28];
    const float* W5 = (const float*)d_in[29];
    const float* mu5 = (const float*)d_in[30];
    const float* is5 = (const float*)d_in[31];
    const float* b5 = (const float*)d_in[32];

    const int E1 = in_sizes[1], E2 = in_sizes[4], E3 = in_sizes[7];
    const int NT_ = N0C + N1C + N2C;

    char* w = (char*)d_ws;
    auto alloc = [&](size_t bytes) {
        void* p = (void*)w;
        w += (bytes + 255) & ~(size_t)255;
        return p;
    };
    int* degs = (int*)alloc((size_t)NT_ * 2 * 4);
    int* deg1 = degs, *deg2 = degs + N0C, *deg3 = degs + N0C + N1C;
    int* cur1 = degs + NT_, *cur2 = cur1 + N0C, *cur3 = cur2 + N1C;
    int* off1 = (int*)alloc(((size_t)N0C + 1) * 4);
    int* off2 = (int*)alloc(((size_t)N1C + 1) * 4);
    int* off3 = (int*)alloc(((size_t)N2C + 1) * 4);
    int* part = (int*)alloc(292 * 4);
    int* csrc1 = (int*)alloc((size_t)E1 * 4);
    float2* cpk1 = (float2*)alloc((size_t)E1 * 8);
    int* csrc2 = (int*)alloc((size_t)E2 * 4);
    float2* cpk2 = (float2*)alloc((size_t)E2 * 8);
    int* csrc3 = (int*)alloc((size_t)E3 * 4);
    float2* cpk3 = (float2*)alloc((size_t)E3 * 8);
    float* inv1 = (float*)alloc((size_t)N0C * 4);
    float* inv2 = (float*)alloc((size_t)N1C * 4);
    float* inv3 = (float*)alloc((size_t)N2C * 4);
    float* g1 = (float*)alloc(((size_t)2 * E1 + 2 * E2 + E3) * 12 * 4);
    float* g5 = g1 + (size_t)E1 * 12;
    float* g2 = g5 + (size_t)E1 * 12;
    float* g4 = g2 + (size_t)E2 * 12;
    float* g3 = g4 + (size_t)E2 * 12;
    _Float16* out0 = (_Float16*)alloc((size_t)N0C * 32 * 2);
    _Float16* out1 = (_Float16*)alloc((size_t)N1C * 64 * 2);
    _Float16* out2 = (_Float16*)alloc((size_t)N2C * 128 * 2);
    _Float16* out3 = (_Float16*)alloc((size_t)N1C * 64 * 2);
    _Float16* hp1 = (_Float16*)alloc((size_t)N1C * 32 * 2);
    _Float16* hp2 = (_Float16*)alloc((size_t)N2C * 64 * 2);
    _Float16* agg2 = (_Float16*)alloc((size_t)N1C * 320 * 2);
    _Float16* agg3 = (_Float16*)alloc((size_t)N2C * 640 * 2);
    _Float16* Wt2 = (_Float16*)alloc((size_t)64 * 320 * 2);
    _Float16* Wt3 = (_Float16*)alloc((size_t)128 * 640 * 2);
    _Float16* Wt4 = (_Float16*)alloc((size_t)64 * 1920 * 2);
    _Float16* Wt5 = (_Float16*)alloc((size_t)48 * 960 * 2);

    const int ET = E1 + E2 + E3;
    const int GT = 2 * E1 + 2 * E2 + E3;

    // ---- CSR build (batched) + weight prep + gw precompute
    hipMemsetAsync(degs, 0, (size_t)NT_ * 2 * 4, stream);
    k_prep_wt<<<cdiv(271360, 256), 256, 0, stream>>>(W1, W2, W3, W4, W5,
                                                     Wt2, Wt3, Wt4, Wt5);
    k_hist3<<<cdiv(ET, 256), 256, 0, stream>>>(dst1, dst2, dst3, deg1, deg2, deg3, E1, E2, E3);
    k_scan1_3<<<292, 256, 0, stream>>>(deg1, off1, deg2, off2, deg3, off3, part);
    k_scan2_3<<<3, 256, 0, stream>>>(part);
    k_scan3_3<<<292, 256, 0, stream>>>(off1, off2, off3, part, deg1, deg2, deg3,
                                       inv1, inv2, inv3, E1, E2, E3);
    k_scatter3<<<cdiv(ET, 256), 256, 0, stream>>>(
        src1, dst1, pkor1, off1, cur1, csrc1, cpk1,
        src2, dst2, pkor2, off2, cur2, csrc2, cpk2,
        src3, dst3, pkor3, off3, cur3, csrc3, cpk3, E1, E2, E3);
    k_gw<<<cdiv(GT, 256), 256, 0, stream>>>(
        cpk1, cpk2, cpk3, mu1, is1, mu5, is5, mu2, is2, mu4, is4, mu3, is3,
        g1, g5, g2, g4, g3, E1, E2, E3);

    // ---- L1 fused: aggregate + mini-GEMM + b1 + relu -> out0 (N0,32) fp16
    k_l1<<<N0C / 256, 256, 0, stream>>>(n_feat, off1, csrc1, g1, inv1, W1, b1, out0);

    // ---- L2: pool -> aggX (Cin=32) -> agg2; GEMM+relu -> out1 (N1,64) fp16
    k_pool8h<<<cdiv(N1C * 32, 256), 256, 0, stream>>>(out0, hp1, N1C * 32, 32);
    k_aggx<8><<<cdiv(N1C, 32), 256, 0, stream>>>(hp1, off2, csrc2, g2, inv2, agg2, N1C);
    k_gemm2<2, 4, 10, 0, 64, 1><<<dim3(1, N1C / 32), 128, 0, stream>>>(agg2, Wt2, nullptr, out1, N1C);

    // ---- L3: pool -> aggX (Cin=64) -> agg3; GEMM+relu -> out2 (N2,128) fp16
    k_pool8h<<<cdiv(N2C * 64, 256), 256, 0, stream>>>(out1, hp2, N2C * 64, 64);
    k_aggx<16><<<cdiv(N2C, 16), 256, 0, stream>>>(hp2, off3, csrc3, g3, inv3, agg3, N2C);
    k_gemm2<1, 8, 20, 0, 128, 1><<<dim3(1, N2C / 16), 64, 0, stream>>>(agg3, Wt3, nullptr, out2, N2C);

    // ---- L4 fused: aggregate + MFMA (NT=4) + relu -> out3 (N1,64) fp16
    k_aggf4<128, 64, 16, 1, 4, 0, 64, 1><<<N1C / 16, 1024, 0, stream>>>(
        out2, out1, off2, csrc2, g4, inv2, Wt4, nullptr, out3, 0);

    // ---- L5 fused: aggregate + MFMA (NT=3) + b5 + tanh -> d_out (N0,40) fp32
    k_aggf4<64, 32, 8, 2, 3, 1, 40, 0><<<N0C / 16, 512, 0, stream>>>(
        out3, out0, off1, csrc1, g5, inv1, Wt5, b5, d_out, 0);
}